// Round 13
// baseline (4056.426 us; speedup 1.0000x reference)
//
#include <hip/hip_runtime.h>
#include <hip/hip_fp16.h>
#include <math.h>

#define B_ 256
#define T_ 256
#define RSS_ 12
#define L_ 256
#define FEAT_ 8
#define H_ 128

// ---------------- workspace layout (4-byte slots) ----------------
constexpr int OFF_PW0  = 0;          // 63488 u32 : [q=0..30][j] uint4 f16-pairs, z0 gate rows
constexpr int OFF_PW1  = 63488;      // 32768    : [q=0..15][j] uint4, Wih1 gate rows (streamed)
constexpr int OFF_W1L  = 96256;      // 32768    : [q=0..15][j] uint4, Whh1 gate rows -> LDS
constexpr int OFF_B0   = 129024;     // 512 f32
constexpr int OFF_B1   = 129536;     // 512
constexpr int OFF_QW1T = 130048;     // [4][64] f32
constexpr int OFF_FC1  = 130304;     // [32][64][4] f32
constexpr int OFF_K2H  = 138496;     // 8192 u32 : uint4[q=0..7][l=0..255] f16-pairs folded keys
constexpr int OFF_KB   = 146688;     // [256]
constexpr int OFF_LF   = 146944;     // [256][8] f32
constexpr int OFF_LPX  = 148992;     // [256]
constexpr int OFF_LPY  = 149248;
constexpr int OFF_LPZ  = 149504;
constexpr int OFF_MEAN = 149760;     // [8]
constexpr int OFF_PREV0= 149768;     // [4]
constexpr int OFF_INT  = 149772;     // ints: ledR[256], cnt[16], idx[12*256]

__device__ __forceinline__ unsigned packh2(float a, float b) {
  const unsigned short lo = __half_as_ushort(__float2half(a));
  const unsigned short hi = __half_as_ushort(__float2half(b));
  return (unsigned)lo | ((unsigned)hi << 16);
}
__device__ __forceinline__ __half2 u2h2(unsigned u){ union { unsigned u; __half2 h; } c; c.u = u; return c.h; }
__device__ __forceinline__ float sigf(float x){ return 1.f/(1.f+expf(-x)); }

#if __has_builtin(__builtin_amdgcn_fdot2)
typedef _Float16 h2v __attribute__((ext_vector_type(2)));
__device__ __forceinline__ float dot2(unsigned w, unsigned z, float acc) {
  union { unsigned u; h2v h; } cw, cz; cw.u = w; cz.u = z;
  return __builtin_amdgcn_fdot2(cw.h, cz.h, acc, false);
}
#else
__device__ __forceinline__ float dot2(unsigned w, unsigned z, float acc) {
  const __half2 hw = u2h2(w), hz = u2h2(z);
  acc = fmaf(__low2float(hw),  __low2float(hz),  acc);
  return fmaf(__high2float(hw), __high2float(hz), acc);
}
#endif

// ---------------- k_prep ----------------
constexpr int SZ_PW0 = 63488, SZ_PW1 = 32768, SZ_W1L = 32768, SZ_B = 512, SZ_Q = 256, SZ_FC = 8192;
constexpr int TOT_T = SZ_PW0 + SZ_PW1 + SZ_W1L + SZ_B + SZ_B + SZ_Q + SZ_FC;

__global__ void k_prep(const float* __restrict__ Wih0, const float* __restrict__ Whh0,
                       const float* __restrict__ bih0, const float* __restrict__ bhh0,
                       const float* __restrict__ Wih1, const float* __restrict__ Whh1,
                       const float* __restrict__ bih1, const float* __restrict__ bhh1,
                       const float* __restrict__ qW1,  const float* __restrict__ fcW1,
                       float* __restrict__ ws) {
  unsigned* wsu = (unsigned*)ws;
  for (int t = blockIdx.x*blockDim.x + threadIdx.x; t < TOT_T; t += gridDim.x*blockDim.x) {
    int u = t;
    if (u < SZ_PW0) {
      const int k = u & 3, j = (u >> 2) & 511, q = u >> 11;   // q 0..30
      const int p = 4*q + k;                                   // pair 0..123
      float lo, hi;
      if (p < 60) {                 // x-part: block r, z=[x,a0..a7,0]
        const int r = p / 5, e0 = 2*(p % 5), e1 = e0 + 1;
        lo = Wih0[j*108 + r*9 + e0];
        hi = (e1 <= 8) ? Wih0[j*108 + r*9 + e1] : 0.f;
      } else {                      // h0-part
        const int i0 = 2*(p - 60);
        lo = Whh0[j*128 + i0]; hi = Whh0[j*128 + i0 + 1];
      }
      wsu[OFF_PW0 + u] = packh2(lo, hi); continue;
    } u -= SZ_PW0;
    if (u < SZ_PW1) {
      const int k = u & 3, j = (u >> 2) & 511, q = u >> 11;
      const int i0 = 2*(4*q + k);
      wsu[OFF_PW1 + u] = packh2(Wih1[j*128 + i0], Wih1[j*128 + i0 + 1]); continue;
    } u -= SZ_PW1;
    if (u < SZ_W1L) {
      const int k = u & 3, j = (u >> 2) & 511, q = u >> 11;
      const int i0 = 2*(4*q + k);
      wsu[OFF_W1L + u] = packh2(Whh1[j*128 + i0], Whh1[j*128 + i0 + 1]); continue;
    } u -= SZ_W1L;
    if (u < SZ_B) { ws[OFF_B0+u] = bih0[u]+bhh0[u]; continue; } u -= SZ_B;
    if (u < SZ_B) { ws[OFF_B1+u] = bih1[u]+bhh1[u]; continue; } u -= SZ_B;
    if (u < SZ_Q) { const int c=u>>6, j=u&63; ws[OFF_QW1T+u] = qW1[j*4+c]; continue; } u -= SZ_Q;
    { const int c = u >> 8, rem = u & 255, j = rem >> 2, k = rem & 3;
      ws[OFF_FC1 + u] = fcW1[j*128 + (c<<2) + k]; }
  }
}

// ---------------- k_led ----------------
__global__ __launch_bounds__(256) void k_led(const float* __restrict__ gplf,
    const float* __restrict__ encW1, const float* __restrict__ encb1,
    const float* __restrict__ encW2, const float* __restrict__ encb2,
    const float* __restrict__ kW1, const float* __restrict__ kb1,
    const float* __restrict__ kW2, const float* __restrict__ kb2,
    const float* __restrict__ qW2, const float* __restrict__ qb2,
    float* __restrict__ ws) {
  __shared__ float sLF[L_][FEAT_];
  __shared__ float sP[L_][3];
  __shared__ int   sR[L_];
  const int l = threadIdx.x;
  const float p0=gplf[l*4+0], p1=gplf[l*4+1], p2=gplf[l*4+2], fr=gplf[l*4+3];

  float e1[32];
  for (int j=0;j<32;++j) {
    float v = encb1[j] + encW1[j*4+0]*p0 + encW1[j*4+1]*p1 + encW1[j*4+2]*p2 + encW1[j*4+3]*fr;
    e1[j] = fmaxf(v,0.f);
  }
  float lf[8];
  for (int f=0;f<8;++f) {
    float v = encb2[f];
    for (int j=0;j<32;++j) v += encW2[f*32+j]*e1[j];
    lf[f] = fmaxf(v,0.f);
  }
  float kin[11] = {lf[0],lf[1],lf[2],lf[3],lf[4],lf[5],lf[6],lf[7],p0,p1,p2};
  float hh[64];
  for (int j=0;j<64;++j) {
    float v = kb1[j];
    for (int c=0;c<11;++c) v += kW1[j*11+c]*kin[c];
    hh[j]=fmaxf(v,0.f);
  }
  float kk[64];
  for (int d=0;d<64;++d) {
    float v = kb2[d];
    for (int j=0;j<64;++j) v += kW2[d*64+j]*hh[j];
    kk[d]=v;
  }
  float kbv=0.f;
  for (int d=0;d<64;++d) kbv += qb2[d]*kk[d];
  ws[OFF_KB+l]=kbv;
  // folded key k2[l][e] = sum_d qW2[d][e]*kk[d]; pack f16 pairs: uint4[q][l] covers e=8q..8q+7
  float k2v[64];
  for (int e=0;e<64;++e) {
    float acc=0.f;
    for (int d=0;d<64;++d) acc += qW2[d*64+e]*kk[d];
    k2v[e]=acc;
  }
  unsigned* wsu = (unsigned*)ws;
  for (int q=0;q<8;++q) {
    uint4 val;
    val.x = packh2(k2v[8*q+0], k2v[8*q+1]);
    val.y = packh2(k2v[8*q+2], k2v[8*q+3]);
    val.z = packh2(k2v[8*q+4], k2v[8*q+5]);
    val.w = packh2(k2v[8*q+6], k2v[8*q+7]);
    ((uint4*)(wsu + OFF_K2H))[q*256 + l] = val;
  }
  for (int f=0;f<8;++f){ ws[OFF_LF+l*8+f]=lf[f]; sLF[l][f]=lf[f]; }
  ws[OFF_LPX+l]=p0; ws[OFF_LPY+l]=p1; ws[OFF_LPZ+l]=p2;
  sP[l][0]=p0; sP[l][1]=p1; sP[l][2]=p2;
  const int r = (int)fr - 1;
  sR[l]=r;
  int* iws = (int*)(ws + OFF_INT);
  iws[l] = r;
  __syncthreads();
  if (l==0) {
    int* cntp = iws + 256;
    int* idxp = cntp + 16;
    int c[12]; for (int r2=0;r2<12;++r2) c[r2]=0;
    for (int i=0;i<L_;++i){ int r2=sR[i]; idxp[r2*256 + c[r2]] = i; c[r2]++; }
    for (int r2=0;r2<12;++r2) cntp[r2]=c[r2];
    float mx=0.f,my=0.f,mz=0.f;
    for (int i=0;i<L_;++i){mx+=sP[i][0];my+=sP[i][1];mz+=sP[i][2];}
    ws[OFF_PREV0+0]=mx/(float)L_; ws[OFF_PREV0+1]=my/(float)L_; ws[OFF_PREV0+2]=mz/(float)L_;
    for (int f=0;f<8;++f){ float s=0.f; for (int i=0;i<L_;++i) s+=sLF[i][f]; ws[OFF_MEAN+f]=s/(float)L_; }
  }
}

// ---------------- main kernel: 512 threads, 2 SAMPLES per block (weight stream amortized) ----------------
__global__ __launch_bounds__(512,1) void k_main(const float* __restrict__ rss,
    const float* __restrict__ qb1, const float* __restrict__ lng, const float* __restrict__ lnb,
    const float* __restrict__ fcb1, const float* __restrict__ fcW2, const float* __restrict__ fcb2,
    const float* __restrict__ ws, float* __restrict__ out) {
  const int b = blockIdx.x, tid = threadIdx.x;
  const int lane = tid & 63, wave = tid >> 6;
  const int j = tid;   // gate index 0..511

  __shared__ uint4 sW1L[8192];                     // 128 KB: Whh1 f16 pairs [q][j]
  __shared__ __align__(16) unsigned saF16[2*12*36];// attn a-matrix f16 pairs, row stride 36
  __shared__ float ssv[2*256];
  __shared__ __align__(16) unsigned sz0h[2*124];   // z0 pairs: [12 x-blocks x5 | h0 x64] per sample
  __shared__ __align__(16) unsigned sz1h[2*128];   // z1 pairs: [h0 x64 | h1 x64] per sample
  __shared__ float sc0[2*128], sc1[2*128];
  __shared__ float sg[2*512];
  __shared__ __align__(16) float syv[2*128];
  __shared__ float sprev[8];
  __shared__ float srxs[24];                       // current-step rss [s][r]
  __shared__ unsigned sLFh[1024];
  __shared__ float sLPx[256], sLPy[256], sLPz[256];
  __shared__ float sKB[256];
  __shared__ float sQ[256], sqb1v[64];
  __shared__ float sLNG[128], sLNB[128];
  __shared__ float sfcb1[64], sfcW2v[192], sfcb2v[4];
  __shared__ float sMEANv[8];
  __shared__ unsigned char sledR8[256];
  __shared__ int scnt[16];
  __shared__ unsigned char sidx8[12*256];

  const unsigned* wsu = (const unsigned*)ws;
  const uint4* PW0g = (const uint4*)(wsu + OFF_PW0);
  const uint4* PW1g = (const uint4*)(wsu + OFF_PW1);
  const uint4* K2Hg = (const uint4*)(wsu + OFF_K2H);
  const float4* F1g = (const float4*)(ws + OFF_FC1);
  const float* B0g = ws + OFF_B0;
  const float* B1g = ws + OFF_B1;

  // ---- one-time LDS staging ----
  {
    const uint4* W1Lg = (const uint4*)(wsu + OFF_W1L);
    for (int u = tid; u < 8192; u += 512) sW1L[u] = W1Lg[u];
    for (int u = tid; u < 1024; u += 512) sLFh[u] = packh2(ws[OFF_LF+2*u], ws[OFF_LF+2*u+1]);
  }
  if (tid < 256) { sLPx[tid]=ws[OFF_LPX+tid]; sLPy[tid]=ws[OFF_LPY+tid]; sLPz[tid]=ws[OFF_LPZ+tid];
                   sKB[tid]=ws[OFF_KB+tid]; sQ[tid]=ws[OFF_QW1T+tid];
                   sc0[tid]=0.f; sc1[tid]=0.f; }
  if (tid < 64) { sqb1v[tid]=qb1[tid]; sfcb1[tid]=fcb1[tid]; }
  if (tid < 128){ sLNG[tid]=lng[tid]; sLNB[tid]=lnb[tid];
                  sz1h[tid]=0u; sz1h[128+tid]=0u; }        // zero both samples' h0-region (and h1 harmlessly)
  if (tid >= 128 && tid < 256) { const int u = tid-128;     // zero z0 h0-part, both samples
                  sz0h[(u>>6)*124 + 60 + (u&63)] = 0u; }
  if (tid < 192) sfcW2v[tid]=fcW2[tid];
  if (tid < 6)  { sfcb2v[tid&3]=fcb2[tid%3]; }             // harmless overlap
  if (tid < 3)  { sfcb2v[tid]=fcb2[tid]; sprev[tid]=ws[OFF_PREV0+tid]; sprev[4+tid]=ws[OFF_PREV0+tid]; }
  if (tid < 8)   sMEANv[tid]=ws[OFF_MEAN+tid];
  {
    const int* iws = (const int*)(ws + OFF_INT);
    if (tid < 256) sledR8[tid]=(unsigned char)iws[tid];
    if (tid < 12)  scnt[tid]=iws[256+tid];
    for (int u = tid; u < 12*256; u += 512) sidx8[u] = (unsigned char)iws[272+u];
  }
  const float* rbase = rss + (size_t)(b*2)*T_*12;
  if (tid < 24) { const int s = tid/12, r = tid%12; srxs[tid] = rbase[(size_t)s*T_*12 + r]; }
  __syncthreads();

  const uint4* z0u4a = (const uint4*)(sz0h);
  const uint4* z0u4b = (const uint4*)(sz0h + 124);
  const uint4* z1u4a = (const uint4*)(sz1h);
  const uint4* z1u4b = (const uint4*)(sz1h + 128);

  for (int t = 0; t < T_; ++t) {
    // (a) relu(q_in @ q_W1^T + q_b1): 2 samples x 12 r x 32 pairs = 768 items
    for (int u = tid; u < 768; u += 512) {
      const int s = (u >= 384), rem = u - s*384;
      const int r = rem >> 5, p = rem & 31;
      const int e0 = 2*p, e1v = e0+1;
      const float xv = srxs[s*12+r];
      const float px = sprev[s*4+0], py = sprev[s*4+1], pz = sprev[s*4+2];
      const float va = fmaxf(sqb1v[e0] + xv*sQ[e0] + px*sQ[64+e0] + py*sQ[128+e0] + pz*sQ[192+e0], 0.f);
      const float vb = fmaxf(sqb1v[e1v] + xv*sQ[e1v] + px*sQ[64+e1v] + py*sQ[128+e1v] + pz*sQ[192+e1v], 0.f);
      saF16[(s*12+r)*36 + p] = packh2(va, vb);
    }
    __syncthreads();

    // (b) scores per LED: thread = (s, l); f16 K2 stream + f16 a-matrix, fdot2
    {
      const int s = tid >> 8, l = tid & 255;
      const int r = sledR8[l];
      const uint4* A4 = (const uint4*)(saF16 + (s*12+r)*36);
      float a0 = sKB[l], a1 = 0.f;
      #pragma unroll
      for (int q = 0; q < 8; ++q) {
        const uint4 K = K2Hg[q*256 + l];
        const uint4 A = A4[q];
        a0 = dot2(K.x, A.x, a0); a1 = dot2(K.y, A.y, a1);
        a0 = dot2(K.z, A.z, a0); a1 = dot2(K.w, A.w, a1);
      }
      const float px = sprev[s*4+0], py = sprev[s*4+1], pz = sprev[s*4+2];
      const float dx = px-sLPx[l], dy = py-sLPy[l], dz = pz-sLPz[l];
      ssv[s*256+l] = a0 + a1 - 0.5f*logf(dx*dx+dy*dy+dz*dz + 1e-8f);
    }
    __syncthreads();

    // (c) masked softmax + aggregation: 24 (s,r) rows over 8 waves, 3 passes
    for (int pass = 0; pass < 3; ++pass) {
      const int rowIdx = wave + pass*8;
      const int s = rowIdx & 1, r = rowIdx >> 1;
      const int cnt = scnt[r];
      float vmax = -3.402823466e38f;
      for (int c = lane; c < cnt; c += 64) vmax = fmaxf(vmax, ssv[s*256 + sidx8[r*256+c]]);
      #pragma unroll
      for (int o = 32; o > 0; o >>= 1) vmax = fmaxf(vmax, __shfl_xor(vmax, o));
      float ps=0.f, p0=0.f,p1=0.f,p2=0.f,p3=0.f,p4=0.f,p5=0.f,p6=0.f,p7=0.f;
      for (int c = lane; c < cnt; c += 64) {
        const int li = sidx8[r*256+c];
        const float p = expf(ssv[s*256+li]-vmax);
        ps += p;
        const unsigned* lf = sLFh + li*4;
        const __half2 A=u2h2(lf[0]), Bq=u2h2(lf[1]), C=u2h2(lf[2]), D=u2h2(lf[3]);
        p0 += p*__low2float(A); p1 += p*__high2float(A);
        p2 += p*__low2float(Bq); p3 += p*__high2float(Bq);
        p4 += p*__low2float(C); p5 += p*__high2float(C);
        p6 += p*__low2float(D); p7 += p*__high2float(D);
      }
      #pragma unroll
      for (int o = 32; o > 0; o >>= 1) {
        ps += __shfl_xor(ps,o);
        p0 += __shfl_xor(p0,o); p1 += __shfl_xor(p1,o);
        p2 += __shfl_xor(p2,o); p3 += __shfl_xor(p3,o);
        p4 += __shfl_xor(p4,o); p5 += __shfl_xor(p5,o);
        p6 += __shfl_xor(p6,o); p7 += __shfl_xor(p7,o);
      }
      if (lane == 0) {
        const float xv = srxs[s*12+r];
        float a0v,a1v,a2v,a3v,a4v,a5v,a6v,a7v;
        if (cnt > 0) {
          const float inv = 1.f/ps;
          a0v=p0*inv; a1v=p1*inv; a2v=p2*inv; a3v=p3*inv;
          a4v=p4*inv; a5v=p5*inv; a6v=p6*inv; a7v=p7*inv;
        } else {
          a0v=sMEANv[0]; a1v=sMEANv[1]; a2v=sMEANv[2]; a3v=sMEANv[3];
          a4v=sMEANv[4]; a5v=sMEANv[5]; a6v=sMEANv[6]; a7v=sMEANv[7];
        }
        unsigned* z0 = sz0h + s*124 + r*5;
        z0[0] = packh2(xv,  a0v);
        z0[1] = packh2(a1v, a2v);
        z0[2] = packh2(a3v, a4v);
        z0[3] = packh2(a5v, a6v);
        z0[4] = packh2(a7v, 0.f);
      }
    }
    __syncthreads();

    // (d1) LSTM0 gates: each W uint4 loaded ONCE, applied to BOTH samples
    {
      const uint4* wp = PW0g + j;
      const float bias = B0g[j];
      float pa0=bias, pa1=0.f, pa2=0.f, pa3=0.f;
      float pb0=bias, pb1=0.f, pb2=0.f, pb3=0.f;
      #pragma unroll
      for (int q = 0; q < 31; ++q) {
        const uint4 W = wp[q*512];
        const uint4 Za = z0u4a[q], Zb = z0u4b[q];
        pa0 = dot2(W.x, Za.x, pa0); pa1 = dot2(W.y, Za.y, pa1);
        pa2 = dot2(W.z, Za.z, pa2); pa3 = dot2(W.w, Za.w, pa3);
        pb0 = dot2(W.x, Zb.x, pb0); pb1 = dot2(W.y, Zb.y, pb1);
        pb2 = dot2(W.z, Zb.z, pb2); pb3 = dot2(W.w, Zb.w, pb3);
      }
      sg[j]     = (pa0+pa1)+(pa2+pa3);
      sg[512+j] = (pb0+pb1)+(pb2+pb3);
    }
    __syncthreads();

    // (d2) LSTM0 nonlinearity: 128 threads = 2 samples x 64 h-pairs
    if (tid < 128) {
      const int s = tid >> 6, v = tid & 63;
      const float* sgS = sg + s*512;
      const float iA=sigf(sgS[2*v]),     iB=sigf(sgS[2*v+1]);
      const float fA=sigf(sgS[128+2*v]), fB=sigf(sgS[128+2*v+1]);
      const float gA=tanhf(sgS[256+2*v]),gB=tanhf(sgS[256+2*v+1]);
      const float oA=sigf(sgS[384+2*v]), oB=sigf(sgS[384+2*v+1]);
      float* c0 = sc0 + s*128;
      const float cA = fA*c0[2*v]   + iA*gA;
      const float cB = fB*c0[2*v+1] + iB*gB;
      c0[2*v] = cA; c0[2*v+1] = cB;
      const float hA = oA*tanhf(cA), hB = oB*tanhf(cB);
      const unsigned hp = packh2(hA, hB);
      sz0h[s*124 + 60 + v] = hp; sz1h[s*128 + v] = hp;
    }
    __syncthreads();

    // (e1) LSTM1 gates: Wih1 streamed (shared), Whh1 from LDS (shared), both samples
    {
      const uint4* wp1 = PW1g + j;
      const float bias = B1g[j];
      float pa0=bias, pa1=0.f, pa2=0.f, pa3=0.f;
      float pb0=bias, pb1=0.f, pb2=0.f, pb3=0.f;
      #pragma unroll
      for (int q = 0; q < 16; ++q) {
        const uint4 W = wp1[q*512];
        const uint4 Za = z1u4a[q], Zb = z1u4b[q];
        pa0 = dot2(W.x, Za.x, pa0); pa1 = dot2(W.y, Za.y, pa1);
        pa2 = dot2(W.z, Za.z, pa2); pa3 = dot2(W.w, Za.w, pa3);
        pb0 = dot2(W.x, Zb.x, pb0); pb1 = dot2(W.y, Zb.y, pb1);
        pb2 = dot2(W.z, Zb.z, pb2); pb3 = dot2(W.w, Zb.w, pb3);
      }
      #pragma unroll 4
      for (int q = 0; q < 16; ++q) {
        const uint4 W = sW1L[q*512 + j];
        const uint4 Za = z1u4a[16+q], Zb = z1u4b[16+q];
        pa0 = dot2(W.x, Za.x, pa0); pa1 = dot2(W.y, Za.y, pa1);
        pa2 = dot2(W.z, Za.z, pa2); pa3 = dot2(W.w, Za.w, pa3);
        pb0 = dot2(W.x, Zb.x, pb0); pb1 = dot2(W.y, Zb.y, pb1);
        pb2 = dot2(W.z, Zb.z, pb2); pb3 = dot2(W.w, Zb.w, pb3);
      }
      sg[j]     = (pa0+pa1)+(pa2+pa3);
      sg[512+j] = (pb0+pb1)+(pb2+pb3);
    }
    __syncthreads();

    // (e2+f+g) 128 threads = 2 samples x 64: LSTM1 nonlin + LN + FC; threads 128-151 stage next rss
    if (tid < 128) {
      const int s = tid >> 6, v = tid & 63;
      const float* sgS = sg + s*512;
      const float iA=sigf(sgS[2*v]),     iB=sigf(sgS[2*v+1]);
      const float fA=sigf(sgS[128+2*v]), fB=sigf(sgS[128+2*v+1]);
      const float gA=tanhf(sgS[256+2*v]),gB=tanhf(sgS[256+2*v+1]);
      const float oA=sigf(sgS[384+2*v]), oB=sigf(sgS[384+2*v+1]);
      float* c1 = sc1 + s*128;
      const float cA = fA*c1[2*v]   + iA*gA;
      const float cB = fB*c1[2*v+1] + iB*gB;
      c1[2*v] = cA; c1[2*v+1] = cB;
      const float hA = oA*tanhf(cA), hB = oB*tanhf(cB);
      sz1h[s*128 + 64 + v] = packh2(hA, hB);
      // LayerNorm within this sample's wave (tid 0-63 = wave0 = s0; 64-127 = wave1 = s1)
      float sum = hA + hB, qs = hA*hA + hB*hB;
      #pragma unroll
      for (int o = 32; o > 0; o >>= 1) { sum += __shfl_xor(sum,o); qs += __shfl_xor(qs,o); }
      const float mu = sum*(1.f/128.f);
      const float rs = 1.f/sqrtf(qs*(1.f/128.f) - mu*mu + 1e-5f);
      const float yA = (hA-mu)*rs*sLNG[2*v] + sLNB[2*v];
      const float yB = (hB-mu)*rs*sLNG[2*v+1] + sLNB[2*v+1];
      float* syS = syv + s*128;
      syS[2*v] = yA; syS[2*v+1] = yB;
      // FC1 (same-wave LDS write->read, no barrier needed)
      float acc = sfcb1[v], acc2 = 0.f;
      const float4* sy4 = (const float4*)syS;
      #pragma unroll 1
      for (int cc = 0; cc < 8; ++cc) {
        const float4 wA = F1g[(cc*4+0)*64 + v];
        const float4 wB = F1g[(cc*4+1)*64 + v];
        const float4 wC = F1g[(cc*4+2)*64 + v];
        const float4 wD = F1g[(cc*4+3)*64 + v];
        const float4 zA = sy4[cc*4+0], zB = sy4[cc*4+1], zC = sy4[cc*4+2], zD = sy4[cc*4+3];
        acc=fmaf(wA.x,zA.x,acc); acc2=fmaf(wA.y,zA.y,acc2); acc=fmaf(wA.z,zA.z,acc); acc2=fmaf(wA.w,zA.w,acc2);
        acc=fmaf(wB.x,zB.x,acc); acc2=fmaf(wB.y,zB.y,acc2); acc=fmaf(wB.z,zB.z,acc); acc2=fmaf(wB.w,zB.w,acc2);
        acc=fmaf(wC.x,zC.x,acc); acc2=fmaf(wC.y,zC.y,acc2); acc=fmaf(wC.z,zC.z,acc); acc2=fmaf(wC.w,zC.w,acc2);
        acc=fmaf(wD.x,zD.x,acc); acc2=fmaf(wD.y,zD.y,acc2); acc=fmaf(wD.z,zD.z,acc); acc2=fmaf(wD.w,zD.w,acc2);
      }
      const float f1 = fmaxf(acc+acc2, 0.f);
      float a0 = sfcW2v[v]*f1, a1 = sfcW2v[64+v]*f1, a2 = sfcW2v[128+v]*f1;
      #pragma unroll
      for (int o = 32; o > 0; o >>= 1) {
        a0 += __shfl_xor(a0,o); a1 += __shfl_xor(a1,o); a2 += __shfl_xor(a2,o);
      }
      if (v < 3) {
        const float r = (v==0 ? a0 : (v==1 ? a1 : a2)) + sfcb2v[v];
        out[((size_t)(b*2+s)*T_+t)*3+v] = r;
        sprev[s*4+v] = r;
      }
    } else if (tid < 152) {
      const int u = tid - 128;               // stage next step's rss
      if (t+1 < T_) {
        const int s = u/12, r = u%12;
        srxs[u] = rbase[(size_t)s*T_*12 + (t+1)*12 + r];
      }
    }
    __syncthreads();
  }
}

extern "C" void kernel_launch(void* const* d_in, const int* in_sizes, int n_in,
                              void* d_out, int out_size, void* d_ws, size_t ws_size,
                              hipStream_t stream) {
  const float* rss   = (const float*)d_in[0];
  const float* gplf  = (const float*)d_in[1];
  const float* encW1 = (const float*)d_in[2];
  const float* encb1 = (const float*)d_in[3];
  const float* encW2 = (const float*)d_in[4];
  const float* encb2 = (const float*)d_in[5];
  const float* qW1   = (const float*)d_in[6];
  const float* qb1   = (const float*)d_in[7];
  const float* qW2   = (const float*)d_in[8];
  const float* qb2   = (const float*)d_in[9];
  const float* kW1   = (const float*)d_in[10];
  const float* kb1   = (const float*)d_in[11];
  const float* kW2   = (const float*)d_in[12];
  const float* kb2   = (const float*)d_in[13];
  const float* Wih0  = (const float*)d_in[14];
  const float* Whh0  = (const float*)d_in[15];
  const float* bih0  = (const float*)d_in[16];
  const float* bhh0  = (const float*)d_in[17];
  const float* Wih1  = (const float*)d_in[18];
  const float* Whh1  = (const float*)d_in[19];
  const float* bih1  = (const float*)d_in[20];
  const float* bhh1  = (const float*)d_in[21];
  const float* lng   = (const float*)d_in[22];
  const float* lnb   = (const float*)d_in[23];
  const float* fcW1  = (const float*)d_in[24];
  const float* fcb1  = (const float*)d_in[25];
  const float* fcW2  = (const float*)d_in[26];
  const float* fcb2  = (const float*)d_in[27];
  float* ws   = (float*)d_ws;
  float* outp = (float*)d_out;

  hipLaunchKernelGGL(k_prep, dim3(256), dim3(256), 0, stream,
                     Wih0,Whh0,bih0,bhh0,Wih1,Whh1,bih1,bhh1,qW1,fcW1,ws);
  hipLaunchKernelGGL(k_led, dim3(1), dim3(256), 0, stream,
                     gplf,encW1,encb1,encW2,encb2,kW1,kb1,kW2,kb2,qW2,qb2,ws);
  hipLaunchKernelGGL(k_main, dim3(B_/2), dim3(512), 0, stream,
                     rss,qb1,lng,lnb,fcb1,fcW2,fcb2,ws,outp);
}

// Round 14
// 3116.692 us; speedup vs baseline: 1.3015x; 1.3015x over previous
//
#include <hip/hip_runtime.h>
#include <hip/hip_fp16.h>
#include <math.h>

#define B_ 256
#define T_ 256
#define RSS_ 12
#define L_ 256
#define FEAT_ 8
#define H_ 128

// Gate-slot permutation: slot j holds gate G = (j&3)*128 + (j>>2)
// -> the 4 gates (i,f,g,o) of h-index (j>>2) occupy 4 ADJACENT lanes.

// ---------------- workspace layout (4-byte slots) ----------------
constexpr int OFF_PW0  = 0;          // 63488 u32 : [q=0..30][slot j] uint4 f16-pairs, z0 gate rows
constexpr int OFF_PW1  = 63488;      // 32768    : [q=0..15][slot j] uint4, Wih1 gate rows
constexpr int OFF_W1L  = 96256;      // 32768    : [q=0..15][slot j] uint4, Whh1 gate rows -> LDS
constexpr int OFF_B0   = 129024;     // 512 f32 (slot-keyed)
constexpr int OFF_B1   = 129536;     // 512
constexpr int OFF_QW1T = 130048;     // [4][64] f32
constexpr int OFF_FC1  = 130304;     // [32][64][4] f32
constexpr int OFF_K2H  = 138496;     // 8192 u32 : uint4[q=0..7][l] f16-pairs folded keys
constexpr int OFF_KB   = 146688;     // [256]
constexpr int OFF_LF   = 146944;     // [256][8] f32
constexpr int OFF_LPX  = 148992;     // [256]
constexpr int OFF_LPY  = 149248;
constexpr int OFF_LPZ  = 149504;
constexpr int OFF_MEAN = 149760;     // [8]
constexpr int OFF_PREV0= 149768;     // [4]
constexpr int OFF_INT  = 149772;     // ints: ledR[256](unused in main), cnt[16], idx[12*256]

__device__ __forceinline__ unsigned packh2(float a, float b) {
  const unsigned short lo = __half_as_ushort(__float2half(a));
  const unsigned short hi = __half_as_ushort(__float2half(b));
  return (unsigned)lo | ((unsigned)hi << 16);
}
__device__ __forceinline__ __half2 u2h2(unsigned u){ union { unsigned u; __half2 h; } c; c.u = u; return c.h; }
__device__ __forceinline__ float sigf(float x){ return 1.f/(1.f+expf(-x)); }

#if __has_builtin(__builtin_amdgcn_fdot2)
typedef _Float16 h2v __attribute__((ext_vector_type(2)));
__device__ __forceinline__ float dot2(unsigned w, unsigned z, float acc) {
  union { unsigned u; h2v h; } cw, cz; cw.u = w; cz.u = z;
  return __builtin_amdgcn_fdot2(cw.h, cz.h, acc, false);
}
#else
__device__ __forceinline__ float dot2(unsigned w, unsigned z, float acc) {
  const __half2 hw = u2h2(w), hz = u2h2(z);
  acc = fmaf(__low2float(hw),  __low2float(hz),  acc);
  return fmaf(__high2float(hw), __high2float(hz), acc);
}
#endif

// Raw barrier: order LDS (lgkmcnt) but leave VMEM (vmcnt) in flight.
__device__ __forceinline__ void bar_lds() {
  asm volatile("s_waitcnt lgkmcnt(0)" ::: "memory");
  __builtin_amdgcn_s_barrier();
  asm volatile("" ::: "memory");
}

// ---------------- k_prep ----------------
constexpr int SZ_PW0 = 63488, SZ_PW1 = 32768, SZ_W1L = 32768, SZ_B = 512, SZ_Q = 256, SZ_FC = 8192;
constexpr int TOT_T = SZ_PW0 + SZ_PW1 + SZ_W1L + SZ_B + SZ_B + SZ_Q + SZ_FC;

__global__ void k_prep(const float* __restrict__ Wih0, const float* __restrict__ Whh0,
                       const float* __restrict__ bih0, const float* __restrict__ bhh0,
                       const float* __restrict__ Wih1, const float* __restrict__ Whh1,
                       const float* __restrict__ bih1, const float* __restrict__ bhh1,
                       const float* __restrict__ qW1,  const float* __restrict__ fcW1,
                       float* __restrict__ ws) {
  unsigned* wsu = (unsigned*)ws;
  for (int t = blockIdx.x*blockDim.x + threadIdx.x; t < TOT_T; t += gridDim.x*blockDim.x) {
    int u = t;
    if (u < SZ_PW0) {
      const int k = u & 3, j = (u >> 2) & 511, q = u >> 11;   // q 0..30, j = slot
      const int G = ((j & 3) << 7) | (j >> 2);                 // gate row
      const int p = 4*q + k;                                   // pair 0..123
      float lo, hi;
      if (p < 60) {                 // x-part: block r, z=[x,a0..a7,0]
        const int r = p / 5, e0 = 2*(p % 5), e1 = e0 + 1;
        lo = Wih0[G*108 + r*9 + e0];
        hi = (e1 <= 8) ? Wih0[G*108 + r*9 + e1] : 0.f;
      } else {                      // h0-part
        const int i0 = 2*(p - 60);
        lo = Whh0[G*128 + i0]; hi = Whh0[G*128 + i0 + 1];
      }
      wsu[OFF_PW0 + u] = packh2(lo, hi); continue;
    } u -= SZ_PW0;
    if (u < SZ_PW1) {
      const int k = u & 3, j = (u >> 2) & 511, q = u >> 11;
      const int G = ((j & 3) << 7) | (j >> 2);
      const int i0 = 2*(4*q + k);
      wsu[OFF_PW1 + u] = packh2(Wih1[G*128 + i0], Wih1[G*128 + i0 + 1]); continue;
    } u -= SZ_PW1;
    if (u < SZ_W1L) {
      const int k = u & 3, j = (u >> 2) & 511, q = u >> 11;
      const int G = ((j & 3) << 7) | (j >> 2);
      const int i0 = 2*(4*q + k);
      wsu[OFF_W1L + u] = packh2(Whh1[G*128 + i0], Whh1[G*128 + i0 + 1]); continue;
    } u -= SZ_W1L;
    if (u < SZ_B) { const int G = ((u&3)<<7)|(u>>2); ws[OFF_B0+u] = bih0[G]+bhh0[G]; continue; } u -= SZ_B;
    if (u < SZ_B) { const int G = ((u&3)<<7)|(u>>2); ws[OFF_B1+u] = bih1[G]+bhh1[G]; continue; } u -= SZ_B;
    if (u < SZ_Q) { const int c=u>>6, j=u&63; ws[OFF_QW1T+u] = qW1[j*4+c]; continue; } u -= SZ_Q;
    { const int c = u >> 8, rem = u & 255, j = rem >> 2, k = rem & 3;
      ws[OFF_FC1 + u] = fcW1[j*128 + (c<<2) + k]; }
  }
}

// ---------------- k_led (as round 13: f16-pair folded keys) ----------------
__global__ __launch_bounds__(256) void k_led(const float* __restrict__ gplf,
    const float* __restrict__ encW1, const float* __restrict__ encb1,
    const float* __restrict__ encW2, const float* __restrict__ encb2,
    const float* __restrict__ kW1, const float* __restrict__ kb1,
    const float* __restrict__ kW2, const float* __restrict__ kb2,
    const float* __restrict__ qW2, const float* __restrict__ qb2,
    float* __restrict__ ws) {
  __shared__ float sLF[L_][FEAT_];
  __shared__ float sP[L_][3];
  __shared__ int   sR[L_];
  const int l = threadIdx.x;
  const float p0=gplf[l*4+0], p1=gplf[l*4+1], p2=gplf[l*4+2], fr=gplf[l*4+3];

  float e1[32];
  for (int j=0;j<32;++j) {
    float v = encb1[j] + encW1[j*4+0]*p0 + encW1[j*4+1]*p1 + encW1[j*4+2]*p2 + encW1[j*4+3]*fr;
    e1[j] = fmaxf(v,0.f);
  }
  float lf[8];
  for (int f=0;f<8;++f) {
    float v = encb2[f];
    for (int j=0;j<32;++j) v += encW2[f*32+j]*e1[j];
    lf[f] = fmaxf(v,0.f);
  }
  float kin[11] = {lf[0],lf[1],lf[2],lf[3],lf[4],lf[5],lf[6],lf[7],p0,p1,p2};
  float hh[64];
  for (int j=0;j<64;++j) {
    float v = kb1[j];
    for (int c=0;c<11;++c) v += kW1[j*11+c]*kin[c];
    hh[j]=fmaxf(v,0.f);
  }
  float kk[64];
  for (int d=0;d<64;++d) {
    float v = kb2[d];
    for (int j=0;j<64;++j) v += kW2[d*64+j]*hh[j];
    kk[d]=v;
  }
  float kbv=0.f;
  for (int d=0;d<64;++d) kbv += qb2[d]*kk[d];
  ws[OFF_KB+l]=kbv;
  float k2v[64];
  for (int e=0;e<64;++e) {
    float acc=0.f;
    for (int d=0;d<64;++d) acc += qW2[d*64+e]*kk[d];
    k2v[e]=acc;
  }
  unsigned* wsu = (unsigned*)ws;
  for (int q=0;q<8;++q) {
    uint4 val;
    val.x = packh2(k2v[8*q+0], k2v[8*q+1]);
    val.y = packh2(k2v[8*q+2], k2v[8*q+3]);
    val.z = packh2(k2v[8*q+4], k2v[8*q+5]);
    val.w = packh2(k2v[8*q+6], k2v[8*q+7]);
    ((uint4*)(wsu + OFF_K2H))[q*256 + l] = val;
  }
  for (int f=0;f<8;++f){ ws[OFF_LF+l*8+f]=lf[f]; sLF[l][f]=lf[f]; }
  ws[OFF_LPX+l]=p0; ws[OFF_LPY+l]=p1; ws[OFF_LPZ+l]=p2;
  sP[l][0]=p0; sP[l][1]=p1; sP[l][2]=p2;
  const int r = (int)fr - 1;
  sR[l]=r;
  int* iws = (int*)(ws + OFF_INT);
  iws[l] = r;
  __syncthreads();
  if (l==0) {
    int* cntp = iws + 256;
    int* idxp = cntp + 16;
    int c[12]; for (int r2=0;r2<12;++r2) c[r2]=0;
    for (int i=0;i<L_;++i){ int r2=sR[i]; idxp[r2*256 + c[r2]] = i; c[r2]++; }
    for (int r2=0;r2<12;++r2) cntp[r2]=c[r2];
    float mx=0.f,my=0.f,mz=0.f;
    for (int i=0;i<L_;++i){mx+=sP[i][0];my+=sP[i][1];mz+=sP[i][2];}
    ws[OFF_PREV0+0]=mx/(float)L_; ws[OFF_PREV0+1]=my/(float)L_; ws[OFF_PREV0+2]=mz/(float)L_;
    for (int f=0;f<8;++f){ float s=0.f; for (int i=0;i<L_;++i) s+=sLF[i][f]; ws[OFF_MEAN+f]=s/(float)L_; }
  }
}

// ---------------- main kernel: 512 thr, 4 raw barriers/step, wave-local attention ----------------
__global__ __launch_bounds__(512,1) void k_main(const float* __restrict__ rss,
    const float* __restrict__ qb1, const float* __restrict__ lng, const float* __restrict__ lnb,
    const float* __restrict__ fcb1, const float* __restrict__ fcW2, const float* __restrict__ fcb2,
    const float* __restrict__ ws, float* __restrict__ out) {
  const int b = blockIdx.x, tid = threadIdx.x;
  const int lane = tid & 63, wave = tid >> 6;
  const int j = tid;   // weight SLOT (gate G = (j&3)*128 + (j>>2))

  __shared__ uint4 sW1L[8192];                    // 128 KB Whh1 (slot-keyed)
  __shared__ __align__(16) unsigned saF16[12*36]; // a-rows f16 pairs
  __shared__ float ssv[256];
  __shared__ __align__(16) unsigned sz0h[124];    // z0 pairs
  __shared__ __align__(16) unsigned sz1h[128];    // z1 pairs
  __shared__ float sc0[128], sc1[128];
  __shared__ __align__(16) float syv[128];
  __shared__ float swred[16];
  __shared__ float sprev[4];
  __shared__ float srxs[12];
  __shared__ unsigned sLFh[1024];
  __shared__ float sLPx[256], sLPy[256], sLPz[256];
  __shared__ float sKB[256];
  __shared__ float sQ[256], sqb1v[64];
  __shared__ float sLNG[128], sLNB[128];
  __shared__ float sfcb1[64], sfcW2v[192], sfcb2v[4];
  __shared__ float sMEANv[8];
  __shared__ int scnt[12];
  __shared__ unsigned char sidx8[12*256];

  const unsigned* wsu = (const unsigned*)ws;
  const uint4* PW0g = (const uint4*)(wsu + OFF_PW0);
  const uint4* PW1g = (const uint4*)(wsu + OFF_PW1);
  const uint4* K2Hg = (const uint4*)(wsu + OFF_K2H);
  const float4* F1g = (const float4*)(ws + OFF_FC1);

  // e1 weights (Wih1, slot-keyed): candidate register residents
#define LW1(Q) const uint4 w1_##Q = PW1g[Q*512 + j];
  LW1(0) LW1(1) LW1(2) LW1(3) LW1(4) LW1(5) LW1(6) LW1(7)
  LW1(8) LW1(9) LW1(10) LW1(11) LW1(12) LW1(13) LW1(14) LW1(15)
  const float biasA = ws[OFF_B0 + j];
  const float biasB = ws[OFF_B1 + j];

  // ---- one-time LDS staging ----
  {
    const uint4* W1Lg = (const uint4*)(wsu + OFF_W1L);
    for (int u = tid; u < 8192; u += 512) sW1L[u] = W1Lg[u];
    for (int u = tid; u < 1024; u += 512) sLFh[u] = packh2(ws[OFF_LF+2*u], ws[OFF_LF+2*u+1]);
  }
  if (tid < 256) { sLPx[tid]=ws[OFF_LPX+tid]; sLPy[tid]=ws[OFF_LPY+tid]; sLPz[tid]=ws[OFF_LPZ+tid];
                   sKB[tid]=ws[OFF_KB+tid]; sQ[tid]=ws[OFF_QW1T+tid]; }
  if (tid < 64) { sqb1v[tid]=qb1[tid]; sfcb1[tid]=fcb1[tid]; }
  if (tid < 128){ sLNG[tid]=lng[tid]; sLNB[tid]=lnb[tid]; sc0[tid]=0.f; sc1[tid]=0.f; sz1h[tid]=0u; }
  if (tid < 192) sfcW2v[tid]=fcW2[tid];
  if (tid < 3)  { sfcb2v[tid]=fcb2[tid]; sprev[tid]=ws[OFF_PREV0+tid]; }
  if (tid < 8)   sMEANv[tid]=ws[OFF_MEAN+tid];
  if (tid < 64)  sz0h[60+tid]=0u;
  {
    const int* iws = (const int*)(ws + OFF_INT);
    if (tid < 12)  scnt[tid]=iws[256+tid];
    for (int u = tid; u < 12*256; u += 512) sidx8[u] = (unsigned char)iws[272+u];
  }
  const float* rb = rss + (size_t)b*T_*12;
  if (tid < 12) srxs[tid] = rb[tid];
  __syncthreads();

  const uint4* z0u4 = (const uint4*)sz0h;
  const uint4* z1u4 = (const uint4*)sz1h;

  for (int t = 0; t < T_; ++t) {
    const float px = sprev[0], py = sprev[1], pz = sprev[2];

    // ---- Phase A (fused a+b+c): wave r handles rows r and r+8, all wave-local ----
    for (int rr = 0; rr < 2; ++rr) {
      if (rr == 1 && wave >= 4) break;
      const int r = wave + rr*8;
      const float xr = srxs[r];
      // a-row: lane = e
      float av = fmaxf(sqb1v[lane] + xr*sQ[lane] + px*sQ[64+lane] + py*sQ[128+lane] + pz*sQ[192+lane], 0.f);
      const float avn = __shfl_down(av, 1);
      if (!(lane & 1)) saF16[r*36 + (lane>>1)] = packh2(av, avn);
      // scores (K2 f16 stream) + row max
      const int cnt = scnt[r];
      const uint4* A4 = (const uint4*)(saF16 + r*36);
      float vmax = -3.402823466e38f;
      for (int c = lane; c < cnt; c += 64) {
        const int li = sidx8[r*256+c];
        float a0 = sKB[li], a1 = 0.f;
        #pragma unroll
        for (int q = 0; q < 8; ++q) {
          const uint4 K = K2Hg[q*256+li];
          const uint4 A = A4[q];
          a0 = dot2(K.x,A.x,a0); a1 = dot2(K.y,A.y,a1);
          a0 = dot2(K.z,A.z,a0); a1 = dot2(K.w,A.w,a1);
        }
        const float dx = px - sLPx[li], dy = py - sLPy[li], dz = pz - sLPz[li];
        const float s = a0 + a1 - 0.5f*logf(dx*dx+dy*dy+dz*dz + 1e-8f);
        ssv[li] = s;
        vmax = fmaxf(vmax, s);
      }
      #pragma unroll
      for (int o = 32; o > 0; o >>= 1) vmax = fmaxf(vmax, __shfl_xor(vmax, o));
      // softmax + aggregation
      float ps=0.f, p0=0.f,p1=0.f,p2=0.f,p3=0.f,p4=0.f,p5=0.f,p6=0.f,p7=0.f;
      for (int c = lane; c < cnt; c += 64) {
        const int li = sidx8[r*256+c];
        const float p = expf(ssv[li]-vmax);
        ps += p;
        const unsigned* lf = sLFh + li*4;
        const __half2 A=u2h2(lf[0]), Bq=u2h2(lf[1]), C=u2h2(lf[2]), D=u2h2(lf[3]);
        p0 += p*__low2float(A); p1 += p*__high2float(A);
        p2 += p*__low2float(Bq); p3 += p*__high2float(Bq);
        p4 += p*__low2float(C); p5 += p*__high2float(C);
        p6 += p*__low2float(D); p7 += p*__high2float(D);
      }
      #pragma unroll
      for (int o = 32; o > 0; o >>= 1) {
        ps += __shfl_xor(ps,o);
        p0 += __shfl_xor(p0,o); p1 += __shfl_xor(p1,o);
        p2 += __shfl_xor(p2,o); p3 += __shfl_xor(p3,o);
        p4 += __shfl_xor(p4,o); p5 += __shfl_xor(p5,o);
        p6 += __shfl_xor(p6,o); p7 += __shfl_xor(p7,o);
      }
      if (lane == 0) {
        float a0v,a1v,a2v,a3v,a4v,a5v,a6v,a7v;
        if (cnt > 0) {
          const float inv = 1.f/ps;
          a0v=p0*inv; a1v=p1*inv; a2v=p2*inv; a3v=p3*inv;
          a4v=p4*inv; a5v=p5*inv; a6v=p6*inv; a7v=p7*inv;
        } else {
          a0v=sMEANv[0]; a1v=sMEANv[1]; a2v=sMEANv[2]; a3v=sMEANv[3];
          a4v=sMEANv[4]; a5v=sMEANv[5]; a6v=sMEANv[6]; a7v=sMEANv[7];
        }
        unsigned* z0 = sz0h + r*5;
        z0[0] = packh2(xr,  a0v);
        z0[1] = packh2(a1v, a2v);
        z0[2] = packh2(a3v, a4v);
        z0[3] = packh2(a5v, a6v);
        z0[4] = packh2(a7v, 0.f);
      }
    }
    bar_lds();

    // ---- Phase B (fused d1+d2): slot j = gate (j&3) of h (j>>2) ----
    {
      const uint4* wp = PW0g + j;
      float g0 = biasA, g1 = 0.f, g2 = 0.f, g3 = 0.f;
      #pragma unroll
      for (int q = 0; q < 31; ++q) {
        const uint4 W = wp[q*512];
        const uint4 Z = z0u4[q];
        g0 = dot2(W.x, Z.x, g0); g1 = dot2(W.y, Z.y, g1);
        g2 = dot2(W.z, Z.z, g2); g3 = dot2(W.w, Z.w, g3);
      }
      const float gp = (g0+g1)+(g2+g3);
      const float gf = __shfl_down(gp, 1);
      const float gg = __shfl_down(gp, 2);
      const float go = __shfl_down(gp, 3);
      const int hidx = j >> 2;
      const float c_in = sc0[hidx];
      const float cv = sigf(gf)*c_in + sigf(gp)*tanhf(gg);
      const float hv = sigf(go)*tanhf(cv);
      if (!(lane & 3)) sc0[hidx] = cv;
      const float hn = __shfl_down(hv, 4);
      if (!(lane & 7)) {
        const unsigned hp = packh2(hv, hn);
        const int v = j >> 3;
        sz0h[60+v] = hp; sz1h[v] = hp;
      }
    }
    bar_lds();

    // ---- Phase C (fused e1 + h1-pack + LN partials) ----
    {
      float g0 = biasB, g1 = 0.f, g2 = 0.f, g3 = 0.f;
#define E1(Q) { const uint4 Z = z1u4[Q]; \
      g0 = dot2(w1_##Q.x, Z.x, g0); g1 = dot2(w1_##Q.y, Z.y, g1); \
      g2 = dot2(w1_##Q.z, Z.z, g2); g3 = dot2(w1_##Q.w, Z.w, g3); }
      E1(0) E1(1) E1(2) E1(3) E1(4) E1(5) E1(6) E1(7)
      E1(8) E1(9) E1(10) E1(11) E1(12) E1(13) E1(14) E1(15)
      #pragma unroll 4
      for (int q = 0; q < 16; ++q) {
        const uint4 W = sW1L[q*512 + j];
        const uint4 Z = z1u4[16+q];
        g0 = dot2(W.x, Z.x, g0); g1 = dot2(W.y, Z.y, g1);
        g2 = dot2(W.z, Z.z, g2); g3 = dot2(W.w, Z.w, g3);
      }
      const float gp = (g0+g1)+(g2+g3);
      const float gf = __shfl_down(gp, 1);
      const float gg = __shfl_down(gp, 2);
      const float go = __shfl_down(gp, 3);
      const int hidx = j >> 2;
      const float c_in = sc1[hidx];
      const float cv = sigf(gf)*c_in + sigf(gp)*tanhf(gg);
      const float hv = sigf(go)*tanhf(cv);
      if (!(lane & 3)) sc1[hidx] = cv;
      const float hn = __shfl_down(hv, 4);
      if (!(lane & 7)) sz1h[64 + (j>>3)] = packh2(hv, hn);
      // LN partials: only lanes =0 mod 4 hold valid hv
      float lv = ((lane & 3) == 0) ? hv : 0.f;
      float lq = ((lane & 3) == 0) ? hv*hv : 0.f;
      #pragma unroll
      for (int o = 32; o > 0; o >>= 1) { lv += __shfl_xor(lv,o); lq += __shfl_xor(lq,o); }
      if (lane == 0) { swred[wave] = lv; swred[8+wave] = lq; }
    }
    bar_lds();

    // ---- Phase D: wave 0 = LN + FC head + out; wave 1 = next rss stage ----
    if (wave == 0) {
      const int v = lane;
      float sum = swred[0]+swred[1]+swred[2]+swred[3]+swred[4]+swred[5]+swred[6]+swred[7];
      float qs  = swred[8]+swred[9]+swred[10]+swred[11]+swred[12]+swred[13]+swred[14]+swred[15];
      const float mu = sum*(1.f/128.f);
      const float rsd = 1.f/sqrtf(qs*(1.f/128.f) - mu*mu + 1e-5f);
      const __half2 hh = u2h2(sz1h[64+v]);
      const float yA = (__low2float(hh)-mu)*rsd*sLNG[2*v] + sLNB[2*v];
      const float yB = (__high2float(hh)-mu)*rsd*sLNG[2*v+1] + sLNB[2*v+1];
      syv[2*v] = yA; syv[2*v+1] = yB;
      float acc = sfcb1[v], acc2 = 0.f;
      const float4* sy4 = (const float4*)syv;
      #pragma unroll 1
      for (int cc = 0; cc < 8; ++cc) {
        const float4 wA = F1g[(cc*4+0)*64 + v];
        const float4 wB = F1g[(cc*4+1)*64 + v];
        const float4 wC = F1g[(cc*4+2)*64 + v];
        const float4 wD = F1g[(cc*4+3)*64 + v];
        const float4 zA = sy4[cc*4+0], zB = sy4[cc*4+1], zC = sy4[cc*4+2], zD = sy4[cc*4+3];
        acc=fmaf(wA.x,zA.x,acc); acc2=fmaf(wA.y,zA.y,acc2); acc=fmaf(wA.z,zA.z,acc); acc2=fmaf(wA.w,zA.w,acc2);
        acc=fmaf(wB.x,zB.x,acc); acc2=fmaf(wB.y,zB.y,acc2); acc=fmaf(wB.z,zB.z,acc); acc2=fmaf(wB.w,zB.w,acc2);
        acc=fmaf(wC.x,zC.x,acc); acc2=fmaf(wC.y,zC.y,acc2); acc=fmaf(wC.z,zC.z,acc); acc2=fmaf(wC.w,zC.w,acc2);
        acc=fmaf(wD.x,zD.x,acc); acc2=fmaf(wD.y,zD.y,acc2); acc=fmaf(wD.z,zD.z,acc); acc2=fmaf(wD.w,zD.w,acc2);
      }
      const float f1 = fmaxf(acc+acc2, 0.f);
      float a0 = sfcW2v[v]*f1, a1 = sfcW2v[64+v]*f1, a2 = sfcW2v[128+v]*f1;
      #pragma unroll
      for (int o = 32; o > 0; o >>= 1) {
        a0 += __shfl_xor(a0,o); a1 += __shfl_xor(a1,o); a2 += __shfl_xor(a2,o);
      }
      if (v < 3) {
        const float r = (v==0 ? a0 : (v==1 ? a1 : a2)) + sfcb2v[v];
        out[((size_t)b*T_+t)*3+v] = r;
        sprev[v] = r;
      }
    } else if (wave == 1) {
      if (lane < 12 && t+1 < T_) srxs[lane] = rb[(t+1)*12 + lane];
    }
    bar_lds();
  }
}

extern "C" void kernel_launch(void* const* d_in, const int* in_sizes, int n_in,
                              void* d_out, int out_size, void* d_ws, size_t ws_size,
                              hipStream_t stream) {
  const float* rss   = (const float*)d_in[0];
  const float* gplf  = (const float*)d_in[1];
  const float* encW1 = (const float*)d_in[2];
  const float* encb1 = (const float*)d_in[3];
  const float* encW2 = (const float*)d_in[4];
  const float* encb2 = (const float*)d_in[5];
  const float* qW1   = (const float*)d_in[6];
  const float* qb1   = (const float*)d_in[7];
  const float* qW2   = (const float*)d_in[8];
  const float* qb2   = (const float*)d_in[9];
  const float* kW1   = (const float*)d_in[10];
  const float* kb1   = (const float*)d_in[11];
  const float* kW2   = (const float*)d_in[12];
  const float* kb2   = (const float*)d_in[13];
  const float* Wih0  = (const float*)d_in[14];
  const float* Whh0  = (const float*)d_in[15];
  const float* bih0  = (const float*)d_in[16];
  const float* bhh0  = (const float*)d_in[17];
  const float* Wih1  = (const float*)d_in[18];
  const float* Whh1  = (const float*)d_in[19];
  const float* bih1  = (const float*)d_in[20];
  const float* bhh1  = (const float*)d_in[21];
  const float* lng   = (const float*)d_in[22];
  const float* lnb   = (const float*)d_in[23];
  const float* fcW1  = (const float*)d_in[24];
  const float* fcb1  = (const float*)d_in[25];
  const float* fcW2  = (const float*)d_in[26];
  const float* fcb2  = (const float*)d_in[27];
  float* ws   = (float*)d_ws;
  float* outp = (float*)d_out;

  hipLaunchKernelGGL(k_prep, dim3(256), dim3(256), 0, stream,
                     Wih0,Whh0,bih0,bhh0,Wih1,Whh1,bih1,bhh1,qW1,fcW1,ws);
  hipLaunchKernelGGL(k_led, dim3(1), dim3(256), 0, stream,
                     gplf,encW1,encb1,encW2,encb2,kW1,kb1,kW2,kb2,qW2,qb2,ws);
  hipLaunchKernelGGL(k_main, dim3(B_), dim3(512), 0, stream,
                     rss,qb1,lng,lnb,fcb1,fcW2,fcb2,ws,outp);
}

// Round 16
// 3099.297 us; speedup vs baseline: 1.3088x; 1.0056x over previous
//
#include <hip/hip_runtime.h>
#include <hip/hip_fp16.h>
#include <math.h>

#define B_ 256
#define T_ 256
#define RSS_ 12
#define L_ 256
#define FEAT_ 8
#define H_ 128

// ---------------- workspace layout (4-byte slots) ----------------
constexpr int OFF_PW0  = 0;                 // 63488 u32 : [q=0..30][j] uint4 f16-pairs, z0 gate rows
constexpr int OFF_PW1  = OFF_PW0 + 63488;   // 32768    : [q=0..15][j] uint4, Wih1 (h0) gate rows
constexpr int OFF_W1L  = OFF_PW1 + 32768;   // 32768    : [q=0..15][j] uint4, Whh1 (h1) gate rows -> LDS
constexpr int OFF_B0   = OFF_W1L + 32768;   // 512 f32
constexpr int OFF_B1   = OFF_B0 + 512;      // 512
constexpr int OFF_QW1T = OFF_B1 + 512;      // [4][64] f32
constexpr int OFF_FC1  = OFF_QW1T + 256;    // [32][64][4] f32
constexpr int OFF_K2T4 = OFF_FC1 + 8192;    // [16][256][4] f32
constexpr int OFF_KB   = OFF_K2T4 + 16384;  // [256]
constexpr int OFF_LF   = OFF_KB + 256;      // [256][8] f32
constexpr int OFF_LPX  = OFF_LF + 2048;     // [256]
constexpr int OFF_LPY  = OFF_LPX + 256;
constexpr int OFF_LPZ  = OFF_LPY + 256;
constexpr int OFF_MEAN = OFF_LPZ + 256;     // [8]
constexpr int OFF_PREV0= OFF_MEAN + 8;      // [4]
constexpr int OFF_INT  = OFF_PREV0 + 4;     // ints: ledR[256], cnt[16], idx[12*256]

__device__ __forceinline__ unsigned packh2(float a, float b) {
  const unsigned short lo = __half_as_ushort(__float2half(a));
  const unsigned short hi = __half_as_ushort(__float2half(b));
  return (unsigned)lo | ((unsigned)hi << 16);
}
__device__ __forceinline__ __half2 u2h2(unsigned u){ union { unsigned u; __half2 h; } c; c.u = u; return c.h; }
__device__ __forceinline__ float sigf(float x){ return 1.f/(1.f+expf(-x)); }

#if __has_builtin(__builtin_amdgcn_fdot2)
typedef _Float16 h2v __attribute__((ext_vector_type(2)));
__device__ __forceinline__ float d2f(unsigned w, unsigned z, float acc) {
  union { unsigned u; h2v h; } cw, cz; cw.u = w; cz.u = z;
  return __builtin_amdgcn_fdot2(cw.h, cz.h, acc, false);
}
#else
__device__ __forceinline__ float d2f(unsigned w, unsigned z, float acc) {
  const __half2 hw = u2h2(w), hz = u2h2(z);
  acc = fmaf(__low2float(hw),  __low2float(hz),  acc);
  return fmaf(__high2float(hw), __high2float(hz), acc);
}
#endif

// lgkm-only barrier: leaves global loads in flight across the phase boundary.
__device__ __forceinline__ void bar_lds() {
  asm volatile("s_waitcnt lgkmcnt(0)" ::: "memory");
  __builtin_amdgcn_s_barrier();
  asm volatile("" ::: "memory");
}

// ---------------- k_prep (identical to round 9) ----------------
constexpr int SZ_PW0 = 63488, SZ_PW1 = 32768, SZ_W1L = 32768, SZ_B = 512, SZ_Q = 256, SZ_FC = 8192;
constexpr int TOT_T = SZ_PW0 + SZ_PW1 + SZ_W1L + SZ_B + SZ_B + SZ_Q + SZ_FC;

__global__ void k_prep(const float* __restrict__ Wih0, const float* __restrict__ Whh0,
                       const float* __restrict__ bih0, const float* __restrict__ bhh0,
                       const float* __restrict__ Wih1, const float* __restrict__ Whh1,
                       const float* __restrict__ bih1, const float* __restrict__ bhh1,
                       const float* __restrict__ qW1,  const float* __restrict__ fcW1,
                       float* __restrict__ ws) {
  unsigned* wsu = (unsigned*)ws;
  for (int t = blockIdx.x*blockDim.x + threadIdx.x; t < TOT_T; t += gridDim.x*blockDim.x) {
    int u = t;
    if (u < SZ_PW0) {
      const int k = u & 3, j = (u >> 2) & 511, q = u >> 11;   // q 0..30
      const int p = 4*q + k;                                   // pair 0..123
      float lo, hi;
      if (p < 60) {                 // x-part: block r, z=[x,a0..a7,0]
        const int r = p / 5, e0 = 2*(p % 5), e1 = e0 + 1;
        lo = Wih0[j*108 + r*9 + e0];
        hi = (e1 <= 8) ? Wih0[j*108 + r*9 + e1] : 0.f;
      } else {                      // h0-part
        const int i0 = 2*(p - 60);
        lo = Whh0[j*128 + i0]; hi = Whh0[j*128 + i0 + 1];
      }
      wsu[OFF_PW0 + u] = packh2(lo, hi); continue;
    } u -= SZ_PW0;
    if (u < SZ_PW1) {
      const int k = u & 3, j = (u >> 2) & 511, q = u >> 11;
      const int i0 = 2*(4*q + k);
      wsu[OFF_PW1 + u] = packh2(Wih1[j*128 + i0], Wih1[j*128 + i0 + 1]); continue;
    } u -= SZ_PW1;
    if (u < SZ_W1L) {
      const int k = u & 3, j = (u >> 2) & 511, q = u >> 11;
      const int i0 = 2*(4*q + k);
      wsu[OFF_W1L + u] = packh2(Whh1[j*128 + i0], Whh1[j*128 + i0 + 1]); continue;
    } u -= SZ_W1L;
    if (u < SZ_B) { ws[OFF_B0+u] = bih0[u]+bhh0[u]; continue; } u -= SZ_B;
    if (u < SZ_B) { ws[OFF_B1+u] = bih1[u]+bhh1[u]; continue; } u -= SZ_B;
    if (u < SZ_Q) { const int c=u>>6, j=u&63; ws[OFF_QW1T+u] = qW1[j*4+c]; continue; } u -= SZ_Q;
    { const int c = u >> 8, rem = u & 255, j = rem >> 2, k = rem & 3;
      ws[OFF_FC1 + u] = fcW1[j*128 + (c<<2) + k]; }
  }
}

// ---------------- k_led (identical to round 9) ----------------
__global__ __launch_bounds__(256) void k_led(const float* __restrict__ gplf,
    const float* __restrict__ encW1, const float* __restrict__ encb1,
    const float* __restrict__ encW2, const float* __restrict__ encb2,
    const float* __restrict__ kW1, const float* __restrict__ kb1,
    const float* __restrict__ kW2, const float* __restrict__ kb2,
    const float* __restrict__ qW2, const float* __restrict__ qb2,
    float* __restrict__ ws) {
  __shared__ float sLF[L_][FEAT_];
  __shared__ float sP[L_][3];
  __shared__ int   sR[L_];
  const int l = threadIdx.x;
  const float p0=gplf[l*4+0], p1=gplf[l*4+1], p2=gplf[l*4+2], fr=gplf[l*4+3];

  float e1[32];
  for (int j=0;j<32;++j) {
    float v = encb1[j] + encW1[j*4+0]*p0 + encW1[j*4+1]*p1 + encW1[j*4+2]*p2 + encW1[j*4+3]*fr;
    e1[j] = fmaxf(v,0.f);
  }
  float lf[8];
  for (int f=0;f<8;++f) {
    float v = encb2[f];
    for (int j=0;j<32;++j) v += encW2[f*32+j]*e1[j];
    lf[f] = fmaxf(v,0.f);
  }
  float kin[11] = {lf[0],lf[1],lf[2],lf[3],lf[4],lf[5],lf[6],lf[7],p0,p1,p2};
  float hh[64];
  for (int j=0;j<64;++j) {
    float v = kb1[j];
    for (int c=0;c<11;++c) v += kW1[j*11+c]*kin[c];
    hh[j]=fmaxf(v,0.f);
  }
  float kk[64];
  for (int d=0;d<64;++d) {
    float v = kb2[d];
    for (int j=0;j<64;++j) v += kW2[d*64+j]*hh[j];
    kk[d]=v;
  }
  float kbv=0.f;
  for (int d=0;d<64;++d) kbv += qb2[d]*kk[d];
  ws[OFF_KB+l]=kbv;
  for (int e=0;e<64;++e) {
    float acc=0.f;
    for (int d=0;d<64;++d) acc += qW2[d*64+e]*kk[d];
    ws[OFF_K2T4 + (e>>2)*1024 + l*4 + (e&3)] = acc;
  }
  for (int f=0;f<8;++f){ ws[OFF_LF+l*8+f]=lf[f]; sLF[l][f]=lf[f]; }
  ws[OFF_LPX+l]=p0; ws[OFF_LPY+l]=p1; ws[OFF_LPZ+l]=p2;
  sP[l][0]=p0; sP[l][1]=p1; sP[l][2]=p2;
  const int r = (int)fr - 1;
  sR[l]=r;
  int* iws = (int*)(ws + OFF_INT);
  iws[l] = r;
  __syncthreads();
  if (l==0) {
    int* cntp = iws + 256;
    int* idxp = cntp + 16;
    int c[12]; for (int r2=0;r2<12;++r2) c[r2]=0;
    for (int i=0;i<L_;++i){ int r2=sR[i]; idxp[r2*256 + c[r2]] = i; c[r2]++; }
    for (int r2=0;r2<12;++r2) cntp[r2]=c[r2];
    float mx=0.f,my=0.f,mz=0.f;
    for (int i=0;i<L_;++i){mx+=sP[i][0];my+=sP[i][1];mz+=sP[i][2];}
    ws[OFF_PREV0+0]=mx/(float)L_; ws[OFF_PREV0+1]=my/(float)L_; ws[OFF_PREV0+2]=mz/(float)L_;
    for (int f=0;f<8;++f){ float s=0.f; for (int i=0;i<L_;++i) s+=sLF[i][f]; ws[OFF_MEAN+f]=s/(float)L_; }
  }
}

// ---------------- main kernel: round-9 structure + pipelined d1 h-half ----------------
__global__ __launch_bounds__(512,1) void k_main(const float* __restrict__ rss,
    const float* __restrict__ qb1, const float* __restrict__ lng, const float* __restrict__ lnb,
    const float* __restrict__ fcb1, const float* __restrict__ fcW2, const float* __restrict__ fcb2,
    const float* __restrict__ ws, float* __restrict__ out) {
  const int b = blockIdx.x, tid = threadIdx.x;
  const int lane = tid & 63, wave = tid >> 6;
  const int j = tid;   // gate index 0..511

  __shared__ uint4 sW1L[8192];                 // 128 KB: Whh1 f16 pairs, [q][j]
  __shared__ unsigned sLFh[1024];
  __shared__ float sLPx[256], sLPy[256], sLPz[256];
  __shared__ float sKB[256];
  __shared__ float sQ[256], sqb1v[64];
  __shared__ float sLNG[128], sLNB[128];
  __shared__ float sfcb1[64], sfcW2v[192], sfcb2v[4];
  __shared__ float sMEANv[8];
  __shared__ __align__(16) unsigned sz0h[124]; // z0 pairs: [12 x-blocks ×5 | h0 ×64]
  __shared__ __align__(16) unsigned sz1h[128]; // z1 pairs: [h0 ×64 | h1 ×64]
  __shared__ float sc0[128], sc1[128];
  __shared__ __align__(16) float sa[12][68];
  __shared__ float ssv[256];
  __shared__ float sg[512];
  __shared__ __align__(16) float syv[128];
  __shared__ float sprev[4];
  __shared__ int   sledR[256], scnt[16];
  __shared__ unsigned short sidx16[12*256];

  const unsigned* wsu = (const unsigned*)ws;
  const uint4* PW0 = (const uint4*)(wsu + OFF_PW0);
  const uint4* PW1 = (const uint4*)(wsu + OFF_PW1);
#define LW1(Q) const uint4 w1_##Q = PW1[Q*512 + j];
  LW1(0) LW1(1) LW1(2) LW1(3) LW1(4) LW1(5) LW1(6) LW1(7)
  LW1(8) LW1(9) LW1(10) LW1(11) LW1(12) LW1(13) LW1(14) LW1(15)
  const float biasA = ws[OFF_B0 + j];
  const float biasB = ws[OFF_B1 + j];

  // ---- one-time LDS staging ----
  {
    const uint4* W1Lg = (const uint4*)(wsu + OFF_W1L);
    for (int u = tid; u < 8192; u += 512) sW1L[u] = W1Lg[u];
    for (int u = tid; u < 1024; u += 512) sLFh[u] = packh2(ws[OFF_LF+2*u], ws[OFF_LF+2*u+1]);
  }
  if (tid < 256) { sLPx[tid]=ws[OFF_LPX+tid]; sLPy[tid]=ws[OFF_LPY+tid]; sLPz[tid]=ws[OFF_LPZ+tid];
                   sKB[tid]=ws[OFF_KB+tid]; sQ[tid]=ws[OFF_QW1T+tid]; }
  if (tid < 64) { sqb1v[tid]=qb1[tid]; sfcb1[tid]=fcb1[tid]; }
  if (tid < 128){ sLNG[tid]=lng[tid]; sLNB[tid]=lnb[tid]; sc0[tid]=0.f; sc1[tid]=0.f; sz1h[tid]=0u; }
  if (tid < 192) sfcW2v[tid]=fcW2[tid];
  if (tid < 3)  { sfcb2v[tid]=fcb2[tid]; sprev[tid]=ws[OFF_PREV0+tid]; }
  if (tid < 8)   sMEANv[tid]=ws[OFF_MEAN+tid];
  if (tid < 64)  sz0h[60+tid]=0u;
  {
    const int* iws = (const int*)(ws + OFF_INT);
    if (tid < 256) sledR[tid]=iws[tid];
    if (tid < 12)  scnt[tid]=iws[256+tid];
    for (int u = tid; u < 12*256; u += 512) sidx16[u] = (unsigned short)iws[272+u];
  }
  __syncthreads();

  const float* rb = rss + (size_t)b*T_*12;
  float x0 = rb[wave];
  float x1 = (wave < 4) ? rb[wave+8] : 0.f;

  const float4* K2g = (const float4*)(ws + OFF_K2T4);
  const float4* F1g = (const float4*)(ws + OFF_FC1);
  const uint4*  z0u4 = (const uint4*)sz0h;
  const uint4*  z1u4 = (const uint4*)sz1h;
  const uint4*  wp0 = PW0 + j;

#define CONSA(V, Q) { const uint4 Z = z0u4[Q]; \
    gA0 = d2f(V.x, Z.x, gA0); gA1 = d2f(V.y, Z.y, gA1); \
    gA2 = d2f(V.z, Z.z, gA2); gA3 = d2f(V.w, Z.w, gA3); }

  for (int t = 0; t < T_; ++t) {
    float xn0 = 0.f, xn1 = 0.f;
    if (t+1 < T_) {
      xn0 = rb[(t+1)*12 + wave];
      if (wave < 4) xn1 = rb[(t+1)*12 + wave+8];
    }
    const float px = sprev[0], py = sprev[1], pz = sprev[2];

    // d1 h-half accumulators; issue window 1 (chunks 15..20) — consumed after (a)
    float gA0 = biasA, gA1 = 0.f, gA2 = 0.f, gA3 = 0.f;
    uint4 c15 = wp0[15*512], c16 = wp0[16*512], c17 = wp0[17*512];
    uint4 c18 = wp0[18*512], c19 = wp0[19*512], c20 = wp0[20*512];

    // (a) relu(q_in @ q_W1^T + q_b1)
    {
      float v = sqb1v[lane] + x0*sQ[lane] + px*sQ[64+lane] + py*sQ[128+lane] + pz*sQ[192+lane];
      sa[wave][lane] = fmaxf(v, 0.f);
      if (wave < 4) {
        float v2 = sqb1v[lane] + x1*sQ[lane] + px*sQ[64+lane] + py*sQ[128+lane] + pz*sQ[192+lane];
        sa[wave+8][lane] = fmaxf(v2, 0.f);
      }
    }
    // consume window 1, issue window 2 (chunks 21..26)
    CONSA(c15,15) CONSA(c16,16) CONSA(c17,17) CONSA(c18,18) CONSA(c19,19) CONSA(c20,20)
    uint4 c21 = wp0[21*512], c22 = wp0[22*512], c23 = wp0[23*512];
    uint4 c24 = wp0[24*512], c25 = wp0[25*512], c26 = wp0[26*512];
    bar_lds();

    // (b) scores per LED (coalesced K2 stream, as round 9)
    if (tid < 256) {
      const int l = tid, r = sledR[l];
      float a0 = sKB[l], a1 = 0.f;
      const float4* ar4 = (const float4*)&sa[r][0];
      #pragma unroll 1
      for (int cc = 0; cc < 4; ++cc) {
        const float4 wA = K2g[(cc*4+0)*256 + l];
        const float4 wB = K2g[(cc*4+1)*256 + l];
        const float4 wC = K2g[(cc*4+2)*256 + l];
        const float4 wD = K2g[(cc*4+3)*256 + l];
        const float4 aA = ar4[cc*4+0], aB = ar4[cc*4+1], aC = ar4[cc*4+2], aD = ar4[cc*4+3];
        a0=fmaf(aA.x,wA.x,a0); a1=fmaf(aA.y,wA.y,a1); a0=fmaf(aA.z,wA.z,a0); a1=fmaf(aA.w,wA.w,a1);
        a0=fmaf(aB.x,wB.x,a0); a1=fmaf(aB.y,wB.y,a1); a0=fmaf(aB.z,wB.z,a0); a1=fmaf(aB.w,wB.w,a1);
        a0=fmaf(aC.x,wC.x,a0); a1=fmaf(aC.y,wC.y,a1); a0=fmaf(aC.z,wC.z,a0); a1=fmaf(aC.w,wC.w,a1);
        a0=fmaf(aD.x,wD.x,a0); a1=fmaf(aD.y,wD.y,a1); a0=fmaf(aD.z,wD.z,a0); a1=fmaf(aD.w,wD.w,a1);
      }
      const float dx = px-sLPx[tid], dy = py-sLPy[tid], dz = pz-sLPz[tid];
      ssv[tid] = a0 + a1 - 0.5f*logf(dx*dx+dy*dy+dz*dz + 1e-8f);
    }
    // consume window 2, issue window 3 (chunks 27..30)
    CONSA(c21,21) CONSA(c22,22) CONSA(c23,23) CONSA(c24,24) CONSA(c25,25) CONSA(c26,26)
    uint4 c27 = wp0[27*512], c28 = wp0[28*512], c29 = wp0[29*512], c30 = wp0[30*512];
    bar_lds();

    // (c) masked softmax + aggregation; writes z0 x-part (uint4 0..14)
    for (int rr = 0; rr < 2; ++rr) {
      if (!(rr == 1 && wave >= 4)) {
        const int r = wave + rr*8;
        const int cnt = scnt[r];
        float vmax = -3.402823466e38f;
        for (int c = lane; c < cnt; c += 64) vmax = fmaxf(vmax, ssv[sidx16[r*256+c]]);
        #pragma unroll
        for (int o = 32; o > 0; o >>= 1) vmax = fmaxf(vmax, __shfl_xor(vmax, o));
        float ps=0.f, p0=0.f,p1=0.f,p2=0.f,p3=0.f,p4=0.f,p5=0.f,p6=0.f,p7=0.f;
        for (int c = lane; c < cnt; c += 64) {
          const int li = sidx16[r*256+c];
          const float p = expf(ssv[li]-vmax);
          ps += p;
          const unsigned* lf = sLFh + li*4;
          const __half2 A=u2h2(lf[0]), Bq=u2h2(lf[1]), C=u2h2(lf[2]), D=u2h2(lf[3]);
          p0 += p*__low2float(A); p1 += p*__high2float(A);
          p2 += p*__low2float(Bq); p3 += p*__high2float(Bq);
          p4 += p*__low2float(C); p5 += p*__high2float(C);
          p6 += p*__low2float(D); p7 += p*__high2float(D);
        }
        #pragma unroll
        for (int o = 32; o > 0; o >>= 1) {
          ps += __shfl_xor(ps,o);
          p0 += __shfl_xor(p0,o); p1 += __shfl_xor(p1,o);
          p2 += __shfl_xor(p2,o); p3 += __shfl_xor(p3,o);
          p4 += __shfl_xor(p4,o); p5 += __shfl_xor(p5,o);
          p6 += __shfl_xor(p6,o); p7 += __shfl_xor(p7,o);
        }
        if (lane == 0) {
          const float xv = rr ? x1 : x0;
          float a0v,a1v,a2v,a3v,a4v,a5v,a6v,a7v;
          if (cnt > 0) {
            const float inv = 1.f/ps;
            a0v=p0*inv; a1v=p1*inv; a2v=p2*inv; a3v=p3*inv;
            a4v=p4*inv; a5v=p5*inv; a6v=p6*inv; a7v=p7*inv;
          } else {
            a0v=sMEANv[0]; a1v=sMEANv[1]; a2v=sMEANv[2]; a3v=sMEANv[3];
            a4v=sMEANv[4]; a5v=sMEANv[5]; a6v=sMEANv[6]; a7v=sMEANv[7];
          }
          sz0h[r*5+0] = packh2(xv,  a0v);
          sz0h[r*5+1] = packh2(a1v, a2v);
          sz0h[r*5+2] = packh2(a3v, a4v);
          sz0h[r*5+3] = packh2(a5v, a6v);
          sz0h[r*5+4] = packh2(a7v, 0.f);
        }
      }
    }
    // consume window 3
    CONSA(c27,27) CONSA(c28,28) CONSA(c29,29) CONSA(c30,30)
    bar_lds();

    // (d1x) x-half chunks 0..14 streamed; finish gate sum
    {
      #pragma unroll
      for (int q = 0; q < 15; ++q) {
        const uint4 W = wp0[q*512];
        const uint4 Z = z0u4[q];
        gA0 = d2f(W.x, Z.x, gA0); gA1 = d2f(W.y, Z.y, gA1);
        gA2 = d2f(W.z, Z.z, gA2); gA3 = d2f(W.w, Z.w, gA3);
      }
      sg[j] = (gA0+gA1)+(gA2+gA3);
    }
    bar_lds();

    // (d2) LSTM0 nonlinearity: wave 0, 2 h-values/thread
    if (tid < 64) {
      const int v = tid;
      const float iA=sigf(sg[2*v]),     iB=sigf(sg[2*v+1]);
      const float fA=sigf(sg[128+2*v]), fB=sigf(sg[128+2*v+1]);
      const float gA=tanhf(sg[256+2*v]),gB=tanhf(sg[256+2*v+1]);
      const float oA=sigf(sg[384+2*v]), oB=sigf(sg[384+2*v+1]);
      const float cA = fA*sc0[2*v]   + iA*gA;
      const float cB = fB*sc0[2*v+1] + iB*gB;
      sc0[2*v] = cA; sc0[2*v+1] = cB;
      const float hA = oA*tanhf(cA), hB = oB*tanhf(cB);
      const unsigned hp = packh2(hA, hB);
      sz0h[60+v] = hp; sz1h[v] = hp;
    }
    bar_lds();

    // (e1) LSTM1 gates: Wih1 (w1_* regs/L2) × h0_t + Whh1 (LDS) × h1_prev
    {
      float g0 = biasB, g1 = 0.f, g2 = 0.f, g3 = 0.f;
#define E1(Q) { const uint4 Z = z1u4[Q]; \
      g0 = d2f(w1_##Q.x, Z.x, g0); g1 = d2f(w1_##Q.y, Z.y, g1); \
      g2 = d2f(w1_##Q.z, Z.z, g2); g3 = d2f(w1_##Q.w, Z.w, g3); }
      E1(0) E1(1) E1(2) E1(3) E1(4) E1(5) E1(6) E1(7)
      E1(8) E1(9) E1(10) E1(11) E1(12) E1(13) E1(14) E1(15)
      #pragma unroll 4
      for (int q = 0; q < 16; ++q) {
        const uint4 W = sW1L[q*512 + j];
        const uint4 Z = z1u4[16+q];
        g0 = d2f(W.x, Z.x, g0); g1 = d2f(W.y, Z.y, g1);
        g2 = d2f(W.z, Z.z, g2); g3 = d2f(W.w, Z.w, g3);
      }
      sg[j] = (g0+g1)+(g2+g3);
    }
    bar_lds();

    // (e2+f+g) wave 0: LSTM1 nonlinearity + LayerNorm + FC head
    if (tid < 64) {
      const int v = tid;
      const float iA=sigf(sg[2*v]),     iB=sigf(sg[2*v+1]);
      const float fA=sigf(sg[128+2*v]), fB=sigf(sg[128+2*v+1]);
      const float gA=tanhf(sg[256+2*v]),gB=tanhf(sg[256+2*v+1]);
      const float oA=sigf(sg[384+2*v]), oB=sigf(sg[384+2*v+1]);
      const float cA = fA*sc1[2*v]   + iA*gA;
      const float cB = fB*sc1[2*v+1] + iB*gB;
      sc1[2*v] = cA; sc1[2*v+1] = cB;
      const float hA = oA*tanhf(cA), hB = oB*tanhf(cB);
      sz1h[64+v] = packh2(hA, hB);
      float s = hA + hB, qs = hA*hA + hB*hB;
      #pragma unroll
      for (int o = 32; o > 0; o >>= 1) { s += __shfl_xor(s,o); qs += __shfl_xor(qs,o); }
      const float mu = s*(1.f/128.f);
      const float rs = 1.f/sqrtf(qs*(1.f/128.f) - mu*mu + 1e-5f);
      const float yA = (hA-mu)*rs*sLNG[2*v] + sLNB[2*v];
      const float yB = (hB-mu)*rs*sLNG[2*v+1] + sLNB[2*v+1];
      syv[2*v] = yA; syv[2*v+1] = yB;
      float acc = sfcb1[v], acc2 = 0.f;
      const float4* sy4 = (const float4*)syv;
      #pragma unroll 1
      for (int cc = 0; cc < 8; ++cc) {
        const float4 wA = F1g[(cc*4+0)*64 + v];
        const float4 wB = F1g[(cc*4+1)*64 + v];
        const float4 wC = F1g[(cc*4+2)*64 + v];
        const float4 wD = F1g[(cc*4+3)*64 + v];
        const float4 zA = sy4[cc*4+0], zB = sy4[cc*4+1], zC = sy4[cc*4+2], zD = sy4[cc*4+3];
        acc=fmaf(wA.x,zA.x,acc); acc2=fmaf(wA.y,zA.y,acc2); acc=fmaf(wA.z,zA.z,acc); acc2=fmaf(wA.w,zA.w,acc2);
        acc=fmaf(wB.x,zB.x,acc); acc2=fmaf(wB.y,zB.y,acc2); acc=fmaf(wB.z,zB.z,acc); acc2=fmaf(wB.w,zB.w,acc2);
        acc=fmaf(wC.x,zC.x,acc); acc2=fmaf(wC.y,zC.y,acc2); acc=fmaf(wC.z,zC.z,acc); acc2=fmaf(wC.w,zC.w,acc2);
        acc=fmaf(wD.x,zD.x,acc); acc2=fmaf(wD.y,zD.y,acc2); acc=fmaf(wD.z,zD.z,acc); acc2=fmaf(wD.w,zD.w,acc2);
      }
      const float f1 = fmaxf(acc+acc2, 0.f);
      float a0 = sfcW2v[v]*f1, a1 = sfcW2v[64+v]*f1, a2 = sfcW2v[128+v]*f1;
      #pragma unroll
      for (int o = 32; o > 0; o >>= 1) {
        a0 += __shfl_xor(a0,o); a1 += __shfl_xor(a1,o); a2 += __shfl_xor(a2,o);
      }
      if (v < 3) {
        const float r = (v==0 ? a0 : (v==1 ? a1 : a2)) + sfcb2v[v];
        out[((size_t)b*T_+t)*3+v] = r;
        sprev[v] = r;
      }
    }
    bar_lds();

    x0 = xn0; x1 = xn1;
  }
}

extern "C" void kernel_launch(void* const* d_in, const int* in_sizes, int n_in,
                              void* d_out, int out_size, void* d_ws, size_t ws_size,
                              hipStream_t stream) {
  const float* rss   = (const float*)d_in[0];
  const float* gplf  = (const float*)d_in[1];
  const float* encW1 = (const float*)d_in[2];
  const float* encb1 = (const float*)d_in[3];
  const float* encW2 = (const float*)d_in[4];
  const float* encb2 = (const float*)d_in[5];
  const float* qW1   = (const float*)d_in[6];
  const float* qb1   = (const float*)d_in[7];
  const float* qW2   = (const float*)d_in[8];
  const float* qb2   = (const float*)d_in[9];
  const float* kW1   = (const float*)d_in[10];
  const float* kb1   = (const float*)d_in[11];
  const float* kW2   = (const float*)d_in[12];
  const float* kb2   = (const float*)d_in[13];
  const float* Wih0  = (const float*)d_in[14];
  const float* Whh0  = (const float*)d_in[15];
  const float* bih0  = (const float*)d_in[16];
  const float* bhh0  = (const float*)d_in[17];
  const float* Wih1  = (const float*)d_in[18];
  const float* Whh1  = (const float*)d_in[19];
  const float* bih1  = (const float*)d_in[20];
  const float* bhh1  = (const float*)d_in[21];
  const float* lng   = (const float*)d_in[22];
  const float* lnb   = (const float*)d_in[23];
  const float* fcW1  = (const float*)d_in[24];
  const float* fcb1  = (const float*)d_in[25];
  const float* fcW2  = (const float*)d_in[26];
  const float* fcb2  = (const float*)d_in[27];
  float* ws   = (float*)d_ws;
  float* outp = (float*)d_out;

  hipLaunchKernelGGL(k_prep, dim3(256), dim3(256), 0, stream,
                     Wih0,Whh0,bih0,bhh0,Wih1,Whh1,bih1,bhh1,qW1,fcW1,ws);
  hipLaunchKernelGGL(k_led, dim3(1), dim3(256), 0, stream,
                     gplf,encW1,encb1,encW2,encb2,kW1,kb1,kW2,kb2,qW2,qb2,ws);
  hipLaunchKernelGGL(k_main, dim3(B_), dim3(512), 0, stream,
                     rss,qb1,lng,lnb,fcb1,fcW2,fcb2,ws,outp);
}

// Round 17
// 2543.906 us; speedup vs baseline: 1.5946x; 1.2183x over previous
//
#include <hip/hip_runtime.h>
#include <hip/hip_fp16.h>
#include <math.h>

#define B_ 256
#define T_ 256
#define RSS_ 12
#define L_ 256
#define FEAT_ 8
#define H_ 128

// ---------------- workspace layout (4-byte slots) ----------------
constexpr int OFF_PW0  = 0;                 // 63488 u32 : [q=0..30][j] uint4 f16-pairs, z0 gate rows
constexpr int OFF_PW1  = OFF_PW0 + 63488;   // 32768    : [q=0..15][j] uint4, Wih1 (h0) gate rows -> regs
constexpr int OFF_W1L  = OFF_PW1 + 32768;   // 32768    : [q=0..15][j] uint4, Whh1 (h1) gate rows -> LDS
constexpr int OFF_B0   = OFF_W1L + 32768;   // 512 f32
constexpr int OFF_B1   = OFF_B0 + 512;      // 512
constexpr int OFF_QW1T = OFF_B1 + 512;      // [4][64] f32
constexpr int OFF_FC1  = OFF_QW1T + 256;    // [32][64][4] f32
constexpr int OFF_K2T4 = OFF_FC1 + 8192;    // [16][256][4] f32
constexpr int OFF_KB   = OFF_K2T4 + 16384;  // [256]
constexpr int OFF_LF   = OFF_KB + 256;      // [256][8] f32
constexpr int OFF_LPX  = OFF_LF + 2048;     // [256]
constexpr int OFF_LPY  = OFF_LPX + 256;
constexpr int OFF_LPZ  = OFF_LPY + 256;
constexpr int OFF_MEAN = OFF_LPZ + 256;     // [8]
constexpr int OFF_PREV0= OFF_MEAN + 8;      // [4]
constexpr int OFF_INT  = OFF_PREV0 + 4;     // ints: ledR[256], cnt[16], idx[12*256]

__device__ __forceinline__ unsigned packh2(float a, float b) {
  const unsigned short lo = __half_as_ushort(__float2half(a));
  const unsigned short hi = __half_as_ushort(__float2half(b));
  return (unsigned)lo | ((unsigned)hi << 16);
}
__device__ __forceinline__ __half2 u2h2(unsigned u){ union { unsigned u; __half2 h; } c; c.u = u; return c.h; }
__device__ __forceinline__ float sigf(float x){ return 1.f/(1.f+expf(-x)); }

// f16-pair dot with f32 accumulate: v_dot2_f32_f16 when available (1 instr), else cvt+fma
#if __has_builtin(__builtin_amdgcn_fdot2)
typedef _Float16 h2v __attribute__((ext_vector_type(2)));
__device__ __forceinline__ float d2(unsigned w, unsigned z, float acc) {
  union { unsigned u; h2v h; } cw, cz; cw.u = w; cz.u = z;
  return __builtin_amdgcn_fdot2(cw.h, cz.h, acc, false);
}
#else
__device__ __forceinline__ float d2(unsigned w, unsigned z, float acc) {
  const __half2 hw = u2h2(w), hz = u2h2(z);
  acc = fmaf(__low2float(hw),  __low2float(hz),  acc);
  return fmaf(__high2float(hw), __high2float(hz), acc);
}
#endif

// ---------------- k_prep ----------------
constexpr int SZ_PW0 = 63488, SZ_PW1 = 32768, SZ_W1L = 32768, SZ_B = 512, SZ_Q = 256, SZ_FC = 8192;
constexpr int TOT_T = SZ_PW0 + SZ_PW1 + SZ_W1L + SZ_B + SZ_B + SZ_Q + SZ_FC;

__global__ void k_prep(const float* __restrict__ Wih0, const float* __restrict__ Whh0,
                       const float* __restrict__ bih0, const float* __restrict__ bhh0,
                       const float* __restrict__ Wih1, const float* __restrict__ Whh1,
                       const float* __restrict__ bih1, const float* __restrict__ bhh1,
                       const float* __restrict__ qW1,  const float* __restrict__ fcW1,
                       float* __restrict__ ws) {
  unsigned* wsu = (unsigned*)ws;
  for (int t = blockIdx.x*blockDim.x + threadIdx.x; t < TOT_T; t += gridDim.x*blockDim.x) {
    int u = t;
    if (u < SZ_PW0) {
      const int k = u & 3, j = (u >> 2) & 511, q = u >> 11;   // q 0..30
      const int p = 4*q + k;                                   // pair 0..123
      float lo, hi;
      if (p < 60) {                 // x-part: block r, z=[x,a0..a7,0]
        const int r = p / 5, e0 = 2*(p % 5), e1 = e0 + 1;
        lo = Wih0[j*108 + r*9 + e0];
        hi = (e1 <= 8) ? Wih0[j*108 + r*9 + e1] : 0.f;
      } else {                      // h0-part
        const int i0 = 2*(p - 60);
        lo = Whh0[j*128 + i0]; hi = Whh0[j*128 + i0 + 1];
      }
      wsu[OFF_PW0 + u] = packh2(lo, hi); continue;
    } u -= SZ_PW0;
    if (u < SZ_PW1) {
      const int k = u & 3, j = (u >> 2) & 511, q = u >> 11;
      const int i0 = 2*(4*q + k);
      wsu[OFF_PW1 + u] = packh2(Wih1[j*128 + i0], Wih1[j*128 + i0 + 1]); continue;
    } u -= SZ_PW1;
    if (u < SZ_W1L) {
      const int k = u & 3, j = (u >> 2) & 511, q = u >> 11;
      const int i0 = 2*(4*q + k);
      wsu[OFF_W1L + u] = packh2(Whh1[j*128 + i0], Whh1[j*128 + i0 + 1]); continue;
    } u -= SZ_W1L;
    if (u < SZ_B) { ws[OFF_B0+u] = bih0[u]+bhh0[u]; continue; } u -= SZ_B;
    if (u < SZ_B) { ws[OFF_B1+u] = bih1[u]+bhh1[u]; continue; } u -= SZ_B;
    if (u < SZ_Q) { const int c=u>>6, j=u&63; ws[OFF_QW1T+u] = qW1[j*4+c]; continue; } u -= SZ_Q;
    { const int c = u >> 8, rem = u & 255, j = rem >> 2, k = rem & 3;
      ws[OFF_FC1 + u] = fcW1[j*128 + (c<<2) + k]; }
  }
}

// ---------------- k_led ----------------
__global__ __launch_bounds__(256) void k_led(const float* __restrict__ gplf,
    const float* __restrict__ encW1, const float* __restrict__ encb1,
    const float* __restrict__ encW2, const float* __restrict__ encb2,
    const float* __restrict__ kW1, const float* __restrict__ kb1,
    const float* __restrict__ kW2, const float* __restrict__ kb2,
    const float* __restrict__ qW2, const float* __restrict__ qb2,
    float* __restrict__ ws) {
  __shared__ float sLF[L_][FEAT_];
  __shared__ float sP[L_][3];
  __shared__ int   sR[L_];
  const int l = threadIdx.x;
  const float p0=gplf[l*4+0], p1=gplf[l*4+1], p2=gplf[l*4+2], fr=gplf[l*4+3];

  float e1[32];
  for (int j=0;j<32;++j) {
    float v = encb1[j] + encW1[j*4+0]*p0 + encW1[j*4+1]*p1 + encW1[j*4+2]*p2 + encW1[j*4+3]*fr;
    e1[j] = fmaxf(v,0.f);
  }
  float lf[8];
  for (int f=0;f<8;++f) {
    float v = encb2[f];
    for (int j=0;j<32;++j) v += encW2[f*32+j]*e1[j];
    lf[f] = fmaxf(v,0.f);
  }
  float kin[11] = {lf[0],lf[1],lf[2],lf[3],lf[4],lf[5],lf[6],lf[7],p0,p1,p2};
  float hh[64];
  for (int j=0;j<64;++j) {
    float v = kb1[j];
    for (int c=0;c<11;++c) v += kW1[j*11+c]*kin[c];
    hh[j]=fmaxf(v,0.f);
  }
  float kk[64];
  for (int d=0;d<64;++d) {
    float v = kb2[d];
    for (int j=0;j<64;++j) v += kW2[d*64+j]*hh[j];
    kk[d]=v;
  }
  float kbv=0.f;
  for (int d=0;d<64;++d) kbv += qb2[d]*kk[d];
  ws[OFF_KB+l]=kbv;
  for (int e=0;e<64;++e) {
    float acc=0.f;
    for (int d=0;d<64;++d) acc += qW2[d*64+e]*kk[d];
    ws[OFF_K2T4 + (e>>2)*1024 + l*4 + (e&3)] = acc;
  }
  for (int f=0;f<8;++f){ ws[OFF_LF+l*8+f]=lf[f]; sLF[l][f]=lf[f]; }
  ws[OFF_LPX+l]=p0; ws[OFF_LPY+l]=p1; ws[OFF_LPZ+l]=p2;
  sP[l][0]=p0; sP[l][1]=p1; sP[l][2]=p2;
  const int r = (int)fr - 1;
  sR[l]=r;
  int* iws = (int*)(ws + OFF_INT);
  iws[l] = r;
  __syncthreads();
  if (l==0) {
    int* cntp = iws + 256;
    int* idxp = cntp + 16;
    int c[12]; for (int r2=0;r2<12;++r2) c[r2]=0;
    for (int i=0;i<L_;++i){ int r2=sR[i]; idxp[r2*256 + c[r2]] = i; c[r2]++; }
    for (int r2=0;r2<12;++r2) cntp[r2]=c[r2];
    float mx=0.f,my=0.f,mz=0.f;
    for (int i=0;i<L_;++i){mx+=sP[i][0];my+=sP[i][1];mz+=sP[i][2];}
    ws[OFF_PREV0+0]=mx/(float)L_; ws[OFF_PREV0+1]=my/(float)L_; ws[OFF_PREV0+2]=mz/(float)L_;
    for (int f=0;f<8;++f){ float s=0.f; for (int i=0;i<L_;++i) s+=sLF[i][f]; ws[OFF_MEAN+f]=s/(float)L_; }
  }
}

// ---------------- main kernel: 512 threads, (512,1) -> round-9 optimum ----------------
__global__ __launch_bounds__(512,1) void k_main(const float* __restrict__ rss,
    const float* __restrict__ qb1, const float* __restrict__ lng, const float* __restrict__ lnb,
    const float* __restrict__ fcb1, const float* __restrict__ fcW2, const float* __restrict__ fcb2,
    const float* __restrict__ ws, float* __restrict__ out) {
  const int b = blockIdx.x, tid = threadIdx.x;
  const int lane = tid & 63, wave = tid >> 6;
  const int j = tid;   // gate index 0..511

  __shared__ uint4 sW1L[8192];                 // 128 KB: LSTM1 h1-half weights, [q][j]
  __shared__ unsigned sLFh[1024];              // led_feat f16 pairs [l][4]
  __shared__ float sLPx[256], sLPy[256], sLPz[256];
  __shared__ float sKB[256];
  __shared__ float sQ[256], sqb1v[64];
  __shared__ float sLNG[128], sLNB[128];
  __shared__ float sfcb1[64], sfcW2v[192], sfcb2v[4];
  __shared__ float sMEANv[8];
  __shared__ __align__(16) unsigned sz0h[124]; // z0 f16 pairs: [12 x-blocks ×5 | h0 ×64]
  __shared__ __align__(16) unsigned sz1h[128]; // z1 f16 pairs: [h0 ×64 | h1 ×64]
  __shared__ float sc0[128], sc1[128];
  __shared__ __align__(16) float sa[12][68];
  __shared__ float ssv[256];
  __shared__ float sg[512];
  __shared__ __align__(16) float syv[128];
  __shared__ float sprev[4];
  __shared__ int   sledR[256], scnt[16];
  __shared__ unsigned short sidx16[12*256];

  // ---- e1 (Wih1) weights: register-resident candidates (64 VGPR) ----
  const uint4* PW0 = (const uint4*)((const unsigned*)ws + OFF_PW0);
  const uint4* PW1 = (const uint4*)((const unsigned*)ws + OFF_PW1);
#define LW1(Q) const uint4 w1_##Q = PW1[Q*512 + j];
  LW1(0) LW1(1) LW1(2) LW1(3) LW1(4) LW1(5) LW1(6) LW1(7)
  LW1(8) LW1(9) LW1(10) LW1(11) LW1(12) LW1(13) LW1(14) LW1(15)
  const float biasA = ws[OFF_B0 + j];
  const float biasB = ws[OFF_B1 + j];

  // ---- one-time LDS staging ----
  {
    const uint4* W1Lg = (const uint4*)((const unsigned*)ws + OFF_W1L);
    for (int u = tid; u < 8192; u += 512) sW1L[u] = W1Lg[u];
    for (int u = tid; u < 1024; u += 512) sLFh[u] = packh2(ws[OFF_LF+2*u], ws[OFF_LF+2*u+1]);
  }
  if (tid < 256) { sLPx[tid]=ws[OFF_LPX+tid]; sLPy[tid]=ws[OFF_LPY+tid]; sLPz[tid]=ws[OFF_LPZ+tid];
                   sKB[tid]=ws[OFF_KB+tid]; sQ[tid]=ws[OFF_QW1T+tid]; }
  if (tid < 64) { sqb1v[tid]=qb1[tid]; sfcb1[tid]=fcb1[tid]; }
  if (tid < 128){ sLNG[tid]=lng[tid]; sLNB[tid]=lnb[tid]; sc0[tid]=0.f; sc1[tid]=0.f; sz1h[tid]=0u; }
  if (tid < 192) sfcW2v[tid]=fcW2[tid];
  if (tid < 3)  { sfcb2v[tid]=fcb2[tid]; sprev[tid]=ws[OFF_PREV0+tid]; }
  if (tid < 8)   sMEANv[tid]=ws[OFF_MEAN+tid];
  if (tid < 64)  sz0h[60+tid]=0u;
  {
    const int* iws = (const int*)(ws + OFF_INT);
    if (tid < 256) sledR[tid]=iws[tid];
    if (tid < 12)  scnt[tid]=iws[256+tid];
    for (int u = tid; u < 12*256; u += 512) sidx16[u] = (unsigned short)iws[272+u];
  }
  __syncthreads();

  const float* rb = rss + (size_t)b*T_*12;
  float x0 = rb[wave];
  float x1 = (wave < 4) ? rb[wave+8] : 0.f;

  const float4* K2g = (const float4*)(ws + OFF_K2T4);
  const float4* F1g = (const float4*)(ws + OFF_FC1);
  const uint4*  z0u4 = (const uint4*)sz0h;
  const uint4*  z1u4 = (const uint4*)sz1h;

  for (int t = 0; t < T_; ++t) {
    float xn0 = 0.f, xn1 = 0.f;
    if (t+1 < T_) {
      xn0 = rb[(t+1)*12 + wave];
      if (wave < 4) xn1 = rb[(t+1)*12 + wave+8];
    }
    const float px = sprev[0], py = sprev[1], pz = sprev[2];

    // (a) relu(q_in @ q_W1^T + q_b1)
    {
      float v = sqb1v[lane] + x0*sQ[lane] + px*sQ[64+lane] + py*sQ[128+lane] + pz*sQ[192+lane];
      sa[wave][lane] = fmaxf(v, 0.f);
      if (wave < 4) {
        float v2 = sqb1v[lane] + x1*sQ[lane] + px*sQ[64+lane] + py*sQ[128+lane] + pz*sQ[192+lane];
        sa[wave+8][lane] = fmaxf(v2, 0.f);
      }
    }
    __syncthreads();

    // (b) scores per LED
    if (tid < 256) {
      const int l = tid, r = sledR[l];
      float a0 = sKB[l], a1 = 0.f;
      const float4* ar4 = (const float4*)&sa[r][0];
      #pragma unroll 1
      for (int cc = 0; cc < 4; ++cc) {
        const float4 wA = K2g[(cc*4+0)*256 + l];
        const float4 wB = K2g[(cc*4+1)*256 + l];
        const float4 wC = K2g[(cc*4+2)*256 + l];
        const float4 wD = K2g[(cc*4+3)*256 + l];
        const float4 aA = ar4[cc*4+0], aB = ar4[cc*4+1], aC = ar4[cc*4+2], aD = ar4[cc*4+3];
        a0=fmaf(aA.x,wA.x,a0); a1=fmaf(aA.y,wA.y,a1); a0=fmaf(aA.z,wA.z,a0); a1=fmaf(aA.w,wA.w,a1);
        a0=fmaf(aB.x,wB.x,a0); a1=fmaf(aB.y,wB.y,a1); a0=fmaf(aB.z,wB.z,a0); a1=fmaf(aB.w,wB.w,a1);
        a0=fmaf(aC.x,wC.x,a0); a1=fmaf(aC.y,wC.y,a1); a0=fmaf(aC.z,wC.z,a0); a1=fmaf(aC.w,wC.w,a1);
        a0=fmaf(aD.x,wD.x,a0); a1=fmaf(aD.y,wD.y,a1); a0=fmaf(aD.z,wD.z,a0); a1=fmaf(aD.w,wD.w,a1);
      }
      const float dx = px-sLPx[tid], dy = py-sLPy[tid], dz = pz-sLPz[tid];
      ssv[tid] = a0 + a1 - 0.5f*logf(dx*dx+dy*dy+dz*dz + 1e-8f);
    }
    __syncthreads();

    // (c) masked softmax + aggregation; pack z0 x-blocks as f16 pairs
    for (int rr = 0; rr < 2; ++rr) {
      if (rr == 1 && wave >= 4) break;
      const int r = wave + rr*8;
      const int cnt = scnt[r];
      float vmax = -3.402823466e38f;
      for (int c = lane; c < cnt; c += 64) vmax = fmaxf(vmax, ssv[sidx16[r*256+c]]);
      #pragma unroll
      for (int o = 32; o > 0; o >>= 1) vmax = fmaxf(vmax, __shfl_xor(vmax, o));
      float ps=0.f, p0=0.f,p1=0.f,p2=0.f,p3=0.f,p4=0.f,p5=0.f,p6=0.f,p7=0.f;
      for (int c = lane; c < cnt; c += 64) {
        const int li = sidx16[r*256+c];
        const float p = expf(ssv[li]-vmax);
        ps += p;
        const unsigned* lf = sLFh + li*4;
        const __half2 A=u2h2(lf[0]), Bq=u2h2(lf[1]), C=u2h2(lf[2]), D=u2h2(lf[3]);
        p0 += p*__low2float(A); p1 += p*__high2float(A);
        p2 += p*__low2float(Bq); p3 += p*__high2float(Bq);
        p4 += p*__low2float(C); p5 += p*__high2float(C);
        p6 += p*__low2float(D); p7 += p*__high2float(D);
      }
      #pragma unroll
      for (int o = 32; o > 0; o >>= 1) {
        ps += __shfl_xor(ps,o);
        p0 += __shfl_xor(p0,o); p1 += __shfl_xor(p1,o);
        p2 += __shfl_xor(p2,o); p3 += __shfl_xor(p3,o);
        p4 += __shfl_xor(p4,o); p5 += __shfl_xor(p5,o);
        p6 += __shfl_xor(p6,o); p7 += __shfl_xor(p7,o);
      }
      if (lane == 0) {
        const float xv = rr ? x1 : x0;
        float a0v,a1v,a2v,a3v,a4v,a5v,a6v,a7v;
        if (cnt > 0) {
          const float inv = 1.f/ps;
          a0v=p0*inv; a1v=p1*inv; a2v=p2*inv; a3v=p3*inv;
          a4v=p4*inv; a5v=p5*inv; a6v=p6*inv; a7v=p7*inv;
        } else {
          a0v=sMEANv[0]; a1v=sMEANv[1]; a2v=sMEANv[2]; a3v=sMEANv[3];
          a4v=sMEANv[4]; a5v=sMEANv[5]; a6v=sMEANv[6]; a7v=sMEANv[7];
        }
        sz0h[r*5+0] = packh2(xv,  a0v);
        sz0h[r*5+1] = packh2(a1v, a2v);
        sz0h[r*5+2] = packh2(a3v, a4v);
        sz0h[r*5+3] = packh2(a5v, a6v);
        sz0h[r*5+4] = packh2(a7v, 0.f);
      }
    }
    __syncthreads();

    // (d1) LSTM0 gates: stream weights from L2 (full unroll), fdot2, 4 accumulators
    {
      float g0 = biasA, g1 = 0.f, g2 = 0.f, g3 = 0.f;
      const uint4* wp = PW0 + j;
      #pragma unroll
      for (int q = 0; q < 31; ++q) {
        const uint4 W = wp[q*512];
        const uint4 Z = z0u4[q];
        g0 = d2(W.x, Z.x, g0); g1 = d2(W.y, Z.y, g1);
        g2 = d2(W.z, Z.z, g2); g3 = d2(W.w, Z.w, g3);
      }
      sg[j] = (g0+g1)+(g2+g3);
    }
    __syncthreads();

    // (d2) LSTM0 nonlinearity: wave 0, 2 h-values/thread
    if (tid < 64) {
      const int v = tid;
      const float iA=sigf(sg[2*v]),     iB=sigf(sg[2*v+1]);
      const float fA=sigf(sg[128+2*v]), fB=sigf(sg[128+2*v+1]);
      const float gA=tanhf(sg[256+2*v]),gB=tanhf(sg[256+2*v+1]);
      const float oA=sigf(sg[384+2*v]), oB=sigf(sg[384+2*v+1]);
      const float cA = fA*sc0[2*v]   + iA*gA;
      const float cB = fB*sc0[2*v+1] + iB*gB;
      sc0[2*v] = cA; sc0[2*v+1] = cB;
      const float hA = oA*tanhf(cA), hB = oB*tanhf(cB);
      const unsigned hp = packh2(hA, hB);
      sz0h[60+v] = hp; sz1h[v] = hp;
    }
    __syncthreads();

    // (e1) LSTM1 gates: h0-half register weights, h1-half LDS weights
    {
      float g0 = biasB, g1 = 0.f, g2 = 0.f, g3 = 0.f;
#define E1(Q) { const uint4 Z = z1u4[Q]; \
      g0 = d2(w1_##Q.x, Z.x, g0); g1 = d2(w1_##Q.y, Z.y, g1); \
      g2 = d2(w1_##Q.z, Z.z, g2); g3 = d2(w1_##Q.w, Z.w, g3); }
      E1(0) E1(1) E1(2) E1(3) E1(4) E1(5) E1(6) E1(7)
      E1(8) E1(9) E1(10) E1(11) E1(12) E1(13) E1(14) E1(15)
      #pragma unroll 4
      for (int q = 0; q < 16; ++q) {
        const uint4 W = sW1L[q*512 + j];
        const uint4 Z = z1u4[16+q];
        g0 = d2(W.x, Z.x, g0); g1 = d2(W.y, Z.y, g1);
        g2 = d2(W.z, Z.z, g2); g3 = d2(W.w, Z.w, g3);
      }
      sg[j] = (g0+g1)+(g2+g3);
    }
    __syncthreads();

    // (e2+f+g) wave 0: LSTM1 nonlinearity + LayerNorm + FC head
    if (tid < 64) {
      const int v = tid;
      const float iA=sigf(sg[2*v]),     iB=sigf(sg[2*v+1]);
      const float fA=sigf(sg[128+2*v]), fB=sigf(sg[128+2*v+1]);
      const float gA=tanhf(sg[256+2*v]),gB=tanhf(sg[256+2*v+1]);
      const float oA=sigf(sg[384+2*v]), oB=sigf(sg[384+2*v+1]);
      const float cA = fA*sc1[2*v]   + iA*gA;
      const float cB = fB*sc1[2*v+1] + iB*gB;
      sc1[2*v] = cA; sc1[2*v+1] = cB;
      const float hA = oA*tanhf(cA), hB = oB*tanhf(cB);
      sz1h[64+v] = packh2(hA, hB);
      float s = hA + hB, qs = hA*hA + hB*hB;
      #pragma unroll
      for (int o = 32; o > 0; o >>= 1) { s += __shfl_xor(s,o); qs += __shfl_xor(qs,o); }
      const float mu = s*(1.f/128.f);
      const float rs = 1.f/sqrtf(qs*(1.f/128.f) - mu*mu + 1e-5f);
      const float yA = (hA-mu)*rs*sLNG[2*v] + sLNB[2*v];
      const float yB = (hB-mu)*rs*sLNG[2*v+1] + sLNB[2*v+1];
      syv[2*v] = yA; syv[2*v+1] = yB;
      float acc = sfcb1[v], acc2 = 0.f;
      const float4* sy4 = (const float4*)syv;
      #pragma unroll 1
      for (int cc = 0; cc < 8; ++cc) {
        const float4 wA = F1g[(cc*4+0)*64 + v];
        const float4 wB = F1g[(cc*4+1)*64 + v];
        const float4 wC = F1g[(cc*4+2)*64 + v];
        const float4 wD = F1g[(cc*4+3)*64 + v];
        const float4 zA = sy4[cc*4+0], zB = sy4[cc*4+1], zC = sy4[cc*4+2], zD = sy4[cc*4+3];
        acc=fmaf(wA.x,zA.x,acc); acc2=fmaf(wA.y,zA.y,acc2); acc=fmaf(wA.z,zA.z,acc); acc2=fmaf(wA.w,zA.w,acc2);
        acc=fmaf(wB.x,zB.x,acc); acc2=fmaf(wB.y,zB.y,acc2); acc=fmaf(wB.z,zB.z,acc); acc2=fmaf(wB.w,zB.w,acc2);
        acc=fmaf(wC.x,zC.x,acc); acc2=fmaf(wC.y,zC.y,acc2); acc=fmaf(wC.z,zC.z,acc); acc2=fmaf(wC.w,zC.w,acc2);
        acc=fmaf(wD.x,zD.x,acc); acc2=fmaf(wD.y,zD.y,acc2); acc=fmaf(wD.z,zD.z,acc); acc2=fmaf(wD.w,zD.w,acc2);
      }
      const float f1 = fmaxf(acc+acc2, 0.f);
      float a0 = sfcW2v[v]*f1, a1 = sfcW2v[64+v]*f1, a2 = sfcW2v[128+v]*f1;
      #pragma unroll
      for (int o = 32; o > 0; o >>= 1) {
        a0 += __shfl_xor(a0,o); a1 += __shfl_xor(a1,o); a2 += __shfl_xor(a2,o);
      }
      if (v < 3) {
        const float r = (v==0 ? a0 : (v==1 ? a1 : a2)) + sfcb2v[v];
        out[((size_t)b*T_+t)*3+v] = r;
        sprev[v] = r;
      }
    }
    __syncthreads();

    x0 = xn0; x1 = xn1;
  }
}

extern "C" void kernel_launch(void* const* d_in, const int* in_sizes, int n_in,
                              void* d_out, int out_size, void* d_ws, size_t ws_size,
                              hipStream_t stream) {
  const float* rss   = (const float*)d_in[0];
  const float* gplf  = (const float*)d_in[1];
  const float* encW1 = (const float*)d_in[2];
  const float* encb1 = (const float*)d_in[3];
  const float* encW2 = (const float*)d_in[4];
  const float* encb2 = (const float*)d_in[5];
  const float* qW1   = (const float*)d_in[6];
  const float* qb1   = (const float*)d_in[7];
  const float* qW2   = (const float*)d_in[8];
  const float* qb2   = (const float*)d_in[9];
  const float* kW1   = (const float*)d_in[10];
  const float* kb1   = (const float*)d_in[11];
  const float* kW2   = (const float*)d_in[12];
  const float* kb2   = (const float*)d_in[13];
  const float* Wih0  = (const float*)d_in[14];
  const float* Whh0  = (const float*)d_in[15];
  const float* bih0  = (const float*)d_in[16];
  const float* bhh0  = (const float*)d_in[17];
  const float* Wih1  = (const float*)d_in[18];
  const float* Whh1  = (const float*)d_in[19];
  const float* bih1  = (const float*)d_in[20];
  const float* bhh1  = (const float*)d_in[21];
  const float* lng   = (const float*)d_in[22];
  const float* lnb   = (const float*)d_in[23];
  const float* fcW1  = (const float*)d_in[24];
  const float* fcb1  = (const float*)d_in[25];
  const float* fcW2  = (const float*)d_in[26];
  const float* fcb2  = (const float*)d_in[27];
  float* ws   = (float*)d_ws;
  float* outp = (float*)d_out;

  hipLaunchKernelGGL(k_prep, dim3(256), dim3(256), 0, stream,
                     Wih0,Whh0,bih0,bhh0,Wih1,Whh1,bih1,bhh1,qW1,fcW1,ws);
  hipLaunchKernelGGL(k_led, dim3(1), dim3(256), 0, stream,
                     gplf,encW1,encb1,encW2,encb2,kW1,kb1,kW2,kb2,qW2,qb2,ws);
  hipLaunchKernelGGL(k_main, dim3(B_), dim3(512), 0, stream,
                     rss,qb1,lng,lnb,fcb1,fcW2,fcb2,ws,outp);
}